// Round 3
// baseline (1532.527 us; speedup 1.0000x reference)
//
#include <hip/hip_runtime.h>

#define N_NODES 50000
#define N_EDGES 800000
#define N_GRAPHS 100
#define FIN_DIM 74
#define H_DIM 256
#define K0PAD 96
#define GEMM_BLOCKS 782   // 2 n-tiles * 391 m-tiles of 128
#define SCAN_BLOCKS 196   // ceil(50000/256)

typedef float f32x4 __attribute__((ext_vector_type(4)));
typedef unsigned short us4 __attribute__((ext_vector_type(4)));
typedef unsigned short us8 __attribute__((ext_vector_type(8)));
typedef __bf16 bf16x8 __attribute__((ext_vector_type(8)));

__device__ __forceinline__ unsigned short f2bf(float x) {
    unsigned u = __builtin_bit_cast(unsigned, x);
    u += 0x7fff + ((u >> 16) & 1);
    return (unsigned short)(u >> 16);
}
__device__ __forceinline__ float bf2f(unsigned short h) {
    return __builtin_bit_cast(float, (unsigned)h << 16);
}

// ---------------- CSR construction (both streams, grid.y selects) ----------------

__global__ void count_kernel(const int* __restrict__ src_a, const int* __restrict__ dst_a,
                             int* __restrict__ cs_a, int* __restrict__ cd_a,
                             const int* __restrict__ src_b, const int* __restrict__ dst_b,
                             int* __restrict__ cs_b, int* __restrict__ cd_b) {
    const int* src = blockIdx.y ? src_b : src_a;
    const int* dst = blockIdx.y ? dst_b : dst_a;
    int* cs = blockIdx.y ? cs_b : cs_a;
    int* cd = blockIdx.y ? cd_b : cd_a;
    int e = blockIdx.x * blockDim.x + threadIdx.x;
    if (e < N_EDGES) {
        atomicAdd(&cs[src[e]], 1);
        atomicAdd(&cd[dst[e]], 1);
    }
}

__global__ void rsqrt_deg_kernel(const int* __restrict__ cs_a, const int* __restrict__ cd_a,
                                 float* __restrict__ dso_a, float* __restrict__ dsi_a,
                                 const int* __restrict__ cs_b, const int* __restrict__ cd_b,
                                 float* __restrict__ dso_b, float* __restrict__ dsi_b) {
    const int* cs = blockIdx.y ? cs_b : cs_a;
    const int* cd = blockIdx.y ? cd_b : cd_a;
    float* dso = blockIdx.y ? dso_b : dso_a;
    float* dsi = blockIdx.y ? dsi_b : dsi_a;
    int i = blockIdx.x * blockDim.x + threadIdx.x;
    if (i < N_NODES) {
        dso[i] = rsqrtf(fmaxf((float)cs[i], 1.0f));
        dsi[i] = rsqrtf(fmaxf((float)cd[i], 1.0f));
    }
}

__device__ __forceinline__ int block_excl_scan(int v, int* wsums) {
    int lane = threadIdx.x & 63, w = threadIdx.x >> 6;
    int x = v;
    #pragma unroll
    for (int ofs = 1; ofs < 64; ofs <<= 1) {
        int y = __shfl_up(x, ofs, 64);
        if (lane >= ofs) x += y;
    }
    if (lane == 63) wsums[w] = x;
    __syncthreads();
    int wo = 0;
    #pragma unroll
    for (int k = 0; k < 4; ++k) if (k < w) wo += wsums[k];
    return wo + x - v;   // exclusive within block
}

// pass 1: per-block exclusive scan of counts; block totals to bs
__global__ void scan1_kernel(const int* __restrict__ cnt_a, int* __restrict__ rp_a, int* __restrict__ bs_a,
                             const int* __restrict__ cnt_b, int* __restrict__ rp_b, int* __restrict__ bs_b) {
    const int* cnt = blockIdx.y ? cnt_b : cnt_a;
    int* rp = blockIdx.y ? rp_b : rp_a;
    int* bs = blockIdx.y ? bs_b : bs_a;
    __shared__ int ws[4];
    int i = blockIdx.x * 256 + threadIdx.x;
    int v = (i < N_NODES) ? cnt[i] : 0;
    int ex = block_excl_scan(v, ws);
    if (i < N_NODES) rp[i] = ex;
    if (threadIdx.x == 255) bs[blockIdx.x] = ex + v;
}

// pass 2: exclusive scan of the block totals (nb <= 256), in place
__global__ void scan2_kernel(int* __restrict__ bs_a, int* __restrict__ bs_b, int nb) {
    int* bs = blockIdx.y ? bs_b : bs_a;
    __shared__ int ws[4];
    int i = threadIdx.x;
    int v = (i < nb) ? bs[i] : 0;
    int ex = block_excl_scan(v, ws);
    __syncthreads();
    if (i < nb) bs[i] = ex;
}

// pass 3: add block offsets; rp[N] = E (total is always E)
__global__ void scan3_kernel(int* __restrict__ rp_a, const int* __restrict__ bs_a,
                             int* __restrict__ rp_b, const int* __restrict__ bs_b) {
    int* rp = blockIdx.y ? rp_b : rp_a;
    const int* bs = blockIdx.y ? bs_b : bs_a;
    int i = blockIdx.x * 256 + threadIdx.x;
    if (i < N_NODES) rp[i] += bs[blockIdx.x];
    if (i == 0) rp[N_NODES] = N_EDGES;
}

__global__ void fill_kernel(const int* __restrict__ src_a, const int* __restrict__ dst_a,
                            const int* __restrict__ rp_a, int* __restrict__ fc_a, int* __restrict__ col_a,
                            const int* __restrict__ src_b, const int* __restrict__ dst_b,
                            const int* __restrict__ rp_b, int* __restrict__ fc_b, int* __restrict__ col_b) {
    const int* src = blockIdx.y ? src_b : src_a;
    const int* dst = blockIdx.y ? dst_b : dst_a;
    const int* rp  = blockIdx.y ? rp_b : rp_a;
    int* fc  = blockIdx.y ? fc_b : fc_a;
    int* col = blockIdx.y ? col_b : col_a;
    int e = blockIdx.x * blockDim.x + threadIdx.x;
    if (e < N_EDGES) {
        int d = dst[e];
        int p = atomicAdd(&fc[d], 1);
        col[rp[d] + p] = src[e];
    }
}

// ---------------- aggregation body: A[n][f] = sum_{s in in(n)} h[s][f]*dso[s] ----------------
// TWO=1: two nodes per block (for F<=128); 4-deep ILP unroll.

template<int F, int LDI, int LDO, int TWO>
__device__ __forceinline__ void agg_node_body(int nb, const float* __restrict__ h,
                                              const float* __restrict__ dso,
                                              const int* __restrict__ rp, const int* __restrict__ col,
                                              float* __restrict__ A) {
    int n, f;
    if (TWO) { n = nb * 2 + (threadIdx.x >> 7); f = threadIdx.x & 127; }
    else     { n = nb; f = threadIdx.x; }
    int beg = rp[n], end = rp[n + 1];
    if (f < F) {
        float acc0 = 0.f, acc1 = 0.f;
        int j = beg;
        for (; j + 3 < end; j += 4) {
            int s0 = col[j], s1 = col[j + 1], s2 = col[j + 2], s3 = col[j + 3];
            float d0 = dso[s0], d1 = dso[s1], d2 = dso[s2], d3 = dso[s3];
            float h0 = h[(size_t)s0 * LDI + f];
            float h1 = h[(size_t)s1 * LDI + f];
            float h2 = h[(size_t)s2 * LDI + f];
            float h3 = h[(size_t)s3 * LDI + f];
            acc0 += h0 * d0 + h1 * d1;
            acc1 += h2 * d2 + h3 * d3;
        }
        for (; j < end; ++j) {
            int s = col[j];
            acc0 += h[(size_t)s * LDI + f] * dso[s];
        }
        A[(size_t)n * LDO + f] = acc0 + acc1;
    } else if (f < LDO) {
        A[(size_t)n * LDO + f] = 0.0f;
    }
}

template<int F, int LDI, int LDO, int TWO>
__global__ void agg_only_kernel(const float* __restrict__ h, const float* __restrict__ dso,
                                const int* __restrict__ rp, const int* __restrict__ col,
                                float* __restrict__ A) {
    agg_node_body<F, LDI, LDO, TWO>(blockIdx.x, h, dso, rp, col, A);
}

// ---------------- MFMA GEMM body (dynamic LDS, 34816 bytes) ----------------
// C[m][j] = relu((A@W)[m][j]*dsi[m] + bias[j]); split bf16 hi/lo, 3 MFMA passes.

template<int K, int KW>
__device__ __forceinline__ void gemm_block_body(int id, const float* __restrict__ A,
                                                const float* __restrict__ W,
                                                const float* __restrict__ bias,
                                                const float* __restrict__ dsi,
                                                float* __restrict__ C, int M,
                                                unsigned short* smem) {
    unsigned short (*Ah)[32] = (unsigned short(*)[32])smem;           // 128x32
    unsigned short (*Al)[32] = Ah + 128;
    unsigned short (*Bh)[36] = (unsigned short(*)[36])(smem + 2 * 128 * 32);
    unsigned short (*Bl)[36] = Bh + 128;

    int tid = threadIdx.x;
    int lane = tid & 63, wid = tid >> 6;
    int wm = (wid >> 1) * 64, wn = (wid & 1) * 64;
    int bm = (id >> 1) * 128, bn = (id & 1) * 128;

    f32x4 acc[4][4] = {};

    int r0 = wm + (lane & 15);
    int c0 = wn + (lane & 15);
    int kA = (lane >> 4) * 8;

    for (int k0 = 0; k0 < K; k0 += 32) {
        #pragma unroll
        for (int i = 0; i < 4; ++i) {
            int q = tid + i * 256;
            int row = q >> 3, k4 = (q & 7) * 4;
            int gm = bm + row;
            f32x4 v = {0.f, 0.f, 0.f, 0.f};
            if (gm < M) v = *(const f32x4*)(A + (size_t)gm * K + k0 + k4);
            us4 h, l;
            #pragma unroll
            for (int j = 0; j < 4; ++j) {
                unsigned short hh = f2bf(v[j]);
                h[j] = hh;
                l[j] = f2bf(v[j] - bf2f(hh));
            }
            *(us4*)&Ah[row][k4] = h;
            *(us4*)&Al[row][k4] = l;
        }
        {
            int col = tid & 127, kg = tid >> 7;
            us4 h[4], l[4];
            #pragma unroll
            for (int g = 0; g < 4; ++g) {
                #pragma unroll
                for (int j = 0; j < 4; ++j) {
                    int gk = k0 + kg * 16 + g * 4 + j;
                    float w = 0.f;
                    if (gk < KW) w = W[(size_t)gk * H_DIM + bn + col];
                    unsigned short hh = f2bf(w);
                    h[g][j] = hh;
                    l[g][j] = f2bf(w - bf2f(hh));
                }
            }
            #pragma unroll
            for (int g = 0; g < 4; ++g) {
                *(us4*)&Bh[col][kg * 16 + g * 4] = h[g];
                *(us4*)&Bl[col][kg * 16 + g * 4] = l[g];
            }
        }
        __syncthreads();

        bf16x8 ah[4], al[4], bh[4], bl[4];
        #pragma unroll
        for (int m = 0; m < 4; ++m) {
            ah[m] = __builtin_bit_cast(bf16x8, *(const us8*)&Ah[r0 + m * 16][kA]);
            al[m] = __builtin_bit_cast(bf16x8, *(const us8*)&Al[r0 + m * 16][kA]);
        }
        #pragma unroll
        for (int n = 0; n < 4; ++n) {
            us4 x0 = *(const us4*)&Bh[c0 + n * 16][kA];
            us4 x1 = *(const us4*)&Bh[c0 + n * 16][kA + 4];
            us8 x;
            x[0] = x0[0]; x[1] = x0[1]; x[2] = x0[2]; x[3] = x0[3];
            x[4] = x1[0]; x[5] = x1[1]; x[6] = x1[2]; x[7] = x1[3];
            bh[n] = __builtin_bit_cast(bf16x8, x);
            us4 y0 = *(const us4*)&Bl[c0 + n * 16][kA];
            us4 y1 = *(const us4*)&Bl[c0 + n * 16][kA + 4];
            us8 y;
            y[0] = y0[0]; y[1] = y0[1]; y[2] = y0[2]; y[3] = y0[3];
            y[4] = y1[0]; y[5] = y1[1]; y[6] = y1[2]; y[7] = y1[3];
            bl[n] = __builtin_bit_cast(bf16x8, y);
        }

        #pragma unroll
        for (int m = 0; m < 4; ++m)
            #pragma unroll
            for (int n = 0; n < 4; ++n) {
                acc[m][n] = __builtin_amdgcn_mfma_f32_16x16x32_bf16(al[m], bh[n], acc[m][n], 0, 0, 0);
                acc[m][n] = __builtin_amdgcn_mfma_f32_16x16x32_bf16(ah[m], bl[n], acc[m][n], 0, 0, 0);
                acc[m][n] = __builtin_amdgcn_mfma_f32_16x16x32_bf16(ah[m], bh[n], acc[m][n], 0, 0, 0);
            }
        __syncthreads();
    }

    int rowq = (lane >> 4) * 4;
    #pragma unroll
    for (int n = 0; n < 4; ++n) {
        int gn = bn + wn + n * 16 + (lane & 15);
        float bv = bias[gn];
        #pragma unroll
        for (int m = 0; m < 4; ++m) {
            #pragma unroll
            for (int j = 0; j < 4; ++j) {
                int gm = bm + wm + m * 16 + rowq + j;
                if (gm < M) {
                    C[(size_t)gm * H_DIM + gn] = fmaxf(acc[m][n][j] * dsi[gm] + bv, 0.0f);
                }
            }
        }
    }
}

template<int K, int KW>
__global__ __launch_bounds__(256, 2) void gemm_only_kernel(
        const float* __restrict__ A, const float* __restrict__ W,
        const float* __restrict__ bias, const float* __restrict__ dsi,
        float* __restrict__ C, int M) {
    extern __shared__ unsigned short smem_us[];
    gemm_block_body<K, KW>(blockIdx.x, A, W, bias, dsi, C, M, smem_us);
}

// ---------------- fused step: blocks [0,n_gemm) do GEMM(stream A), rest do aggregate(stream B) ----

template<int K, int KW, int F, int LDI, int LDO, int TWO>
__global__ __launch_bounds__(256, 2) void fused_step(
        const float* __restrict__ Ag, const float* __restrict__ Wg,
        const float* __restrict__ bg, const float* __restrict__ dsig,
        float* __restrict__ Cg, int M, int n_gemm,
        const float* __restrict__ hA, const float* __restrict__ dsoA,
        const int* __restrict__ rpA, const int* __restrict__ colA,
        float* __restrict__ outA) {
    extern __shared__ unsigned short smem_us[];
    if ((int)blockIdx.x < n_gemm) {
        gemm_block_body<K, KW>(blockIdx.x, Ag, Wg, bg, dsig, Cg, M, smem_us);
    } else {
        agg_node_body<F, LDI, LDO, TWO>(blockIdx.x - n_gemm, hA, dsoA, rpA, colA, outA);
    }
}

// ---------------- pooling ----------------

__global__ void pool_kernel(const float* __restrict__ h, const int* __restrict__ gid,
                            float* __restrict__ pool) {
    int n0 = blockIdx.x * 64;
    int f = threadIdx.x;
    int end = min(n0 + 64, N_NODES);
    float acc = 0.0f;
    int gcur = gid[n0];
    for (int i = n0; i < end; ++i) {
        int g = gid[i];
        if (g != gcur) {
            atomicAdd(&pool[(size_t)gcur * H_DIM + f], acc);
            acc = 0.0f;
            gcur = g;
        }
        acc += h[(size_t)i * H_DIM + f];
    }
    atomicAdd(&pool[(size_t)gcur * H_DIM + f], acc);
}

// ---------------- final MLP ----------------

__global__ __launch_bounds__(256) void mlp_kernel(
        const float* __restrict__ pl, const float* __restrict__ pr,
        const float* __restrict__ Wf1, const float* __restrict__ bf1,
        const float* __restrict__ Wf2, const float* __restrict__ bf2,
        float* __restrict__ out) {
    __shared__ float z[512];
    __shared__ float red[256];
    int g = blockIdx.x, tid = threadIdx.x;
    z[tid] = pl[(size_t)g * H_DIM + tid];
    z[tid + 256] = pr[(size_t)g * H_DIM + tid];
    __syncthreads();
    float t = bf1[tid];
    #pragma unroll 8
    for (int k = 0; k < 512; ++k) t += z[k] * Wf1[(size_t)k * H_DIM + tid];
    t = fmaxf(t, 0.0f);
    red[tid] = t * Wf2[tid];
    __syncthreads();
    for (int ofs = 128; ofs > 0; ofs >>= 1) {
        if (tid < ofs) red[tid] += red[tid + ofs];
        __syncthreads();
    }
    if (tid == 0) out[g] = red[0] + bf2[0];
}

// ---------------- driver ----------------

extern "C" void kernel_launch(void* const* d_in, const int* in_sizes, int n_in,
                              void* d_out, int out_size, void* d_ws, size_t ws_size,
                              hipStream_t stream) {
    const float* xl   = (const float*)d_in[0];
    const float* xr   = (const float*)d_in[1];
    const int* src_l  = (const int*)d_in[2];
    const int* dst_l  = (const int*)d_in[3];
    const int* src_r  = (const int*)d_in[4];
    const int* dst_r  = (const int*)d_in[5];
    const int* gid_l  = (const int*)d_in[6];
    const int* gid_r  = (const int*)d_in[7];
    const float* W0   = (const float*)d_in[8];
    const float* b0   = (const float*)d_in[9];
    const float* W1   = (const float*)d_in[10];
    const float* b1   = (const float*)d_in[11];
    const float* W2   = (const float*)d_in[12];
    const float* b2   = (const float*)d_in[13];
    const float* Wf1  = (const float*)d_in[14];
    const float* bf1  = (const float*)d_in[15];
    const float* Wf2  = (const float*)d_in[16];
    const float* bf2  = (const float*)d_in[17];
    float* out = (float*)d_out;
    (void)in_sizes; (void)n_in; (void)out_size;

    size_t off = 0;
    auto carve = [&](size_t bytes) {
        void* p = (char*)d_ws + off;
        off += (bytes + 255) & ~(size_t)255;
        return p;
    };
    const size_t NB4 = (size_t)N_NODES * 4;

    // --- zero zone (one memset covers all) ---
    char* zstart = (char*)d_ws;
    int*   cnt_s_l = (int*)carve(NB4);
    int*   cnt_d_l = (int*)carve(NB4);
    int*   fillc_l = (int*)carve(NB4);
    int*   cnt_s_r = (int*)carve(NB4);
    int*   cnt_d_r = (int*)carve(NB4);
    int*   fillc_r = (int*)carve(NB4);
    float* pool_l  = (float*)carve((size_t)N_GRAPHS * H_DIM * 4);
    float* pool_r  = (float*)carve((size_t)N_GRAPHS * H_DIM * 4);
    size_t zbytes = off;

    float* dso_l = (float*)carve(NB4);
    float* dsi_l = (float*)carve(NB4);
    float* dso_r = (float*)carve(NB4);
    float* dsi_r = (float*)carve(NB4);
    int*   rp_l  = (int*)carve((size_t)(N_NODES + 1) * 4);
    int*   rp_r  = (int*)carve((size_t)(N_NODES + 1) * 4);
    int*   col_l = (int*)carve((size_t)N_EDGES * 4);
    int*   col_r = (int*)carve((size_t)N_EDGES * 4);
    int*   bs_l  = (int*)carve((size_t)SCAN_BLOCKS * 4);
    int*   bs_r  = (int*)carve((size_t)SCAN_BLOCKS * 4);

    const size_t BIG = (size_t)N_NODES * H_DIM * 4;
    float* bufA_l = (float*)carve(BIG);
    float* bufH_l = (float*)carve(BIG);
    size_t off2 = off;
    float* bufA_r = (float*)carve(BIG);
    float* bufH_r = (float*)carve(BIG);
    bool pipelined = (off <= ws_size);
    if (!pipelined) { bufA_r = bufA_l; bufH_r = bufH_l; off = off2; }

    hipMemsetAsync(zstart, 0, zbytes, stream);

    const int EB = 256, EG = (N_EDGES + EB - 1) / EB;
    const int NG = (N_NODES + 255) / 256;
    const size_t SMEM = 2 * 128 * 32 * 2 + 2 * 128 * 36 * 2;  // 34816 B

    // --- CSR for both streams ---
    count_kernel<<<dim3(EG, 2), EB, 0, stream>>>(src_l, dst_l, cnt_s_l, cnt_d_l,
                                                 src_r, dst_r, cnt_s_r, cnt_d_r);
    rsqrt_deg_kernel<<<dim3(NG, 2), 256, 0, stream>>>(cnt_s_l, cnt_d_l, dso_l, dsi_l,
                                                      cnt_s_r, cnt_d_r, dso_r, dsi_r);
    scan1_kernel<<<dim3(SCAN_BLOCKS, 2), 256, 0, stream>>>(cnt_d_l, rp_l, bs_l, cnt_d_r, rp_r, bs_r);
    scan2_kernel<<<dim3(1, 2), 256, 0, stream>>>(bs_l, bs_r, SCAN_BLOCKS);
    scan3_kernel<<<dim3(SCAN_BLOCKS, 2), 256, 0, stream>>>(rp_l, bs_l, rp_r, bs_r);
    fill_kernel<<<dim3(EG, 2), EB, 0, stream>>>(src_l, dst_l, rp_l, fillc_l, col_l,
                                                src_r, dst_r, rp_r, fillc_r, col_r);

    if (pipelined) {
        // S1: aggL0 (slim kernel, high occupancy)
        agg_only_kernel<FIN_DIM, FIN_DIM, K0PAD, 1><<<N_NODES / 2, 256, 0, stream>>>(
            xl, dso_l, rp_l, col_l, bufA_l);
        // S2: gemmL0 || aggR0
        fused_step<K0PAD, FIN_DIM, FIN_DIM, FIN_DIM, K0PAD, 1>
            <<<GEMM_BLOCKS + N_NODES / 2, 256, SMEM, stream>>>(
            bufA_l, W0, b0, dsi_l, bufH_l, N_NODES, GEMM_BLOCKS,
            xr, dso_r, rp_r, col_r, bufA_r);
        // S3: gemmR0 || aggL1
        fused_step<K0PAD, FIN_DIM, H_DIM, H_DIM, H_DIM, 0>
            <<<GEMM_BLOCKS + N_NODES, 256, SMEM, stream>>>(
            bufA_r, W0, b0, dsi_r, bufH_r, N_NODES, GEMM_BLOCKS,
            bufH_l, dso_l, rp_l, col_l, bufA_l);
        // S4: gemmL1 || aggR1
        fused_step<H_DIM, H_DIM, H_DIM, H_DIM, H_DIM, 0>
            <<<GEMM_BLOCKS + N_NODES, 256, SMEM, stream>>>(
            bufA_l, W1, b1, dsi_l, bufH_l, N_NODES, GEMM_BLOCKS,
            bufH_r, dso_r, rp_r, col_r, bufA_r);
        // S5: gemmR1 || aggL2
        fused_step<H_DIM, H_DIM, H_DIM, H_DIM, H_DIM, 0>
            <<<GEMM_BLOCKS + N_NODES, 256, SMEM, stream>>>(
            bufA_r, W1, b1, dsi_r, bufH_r, N_NODES, GEMM_BLOCKS,
            bufH_l, dso_l, rp_l, col_l, bufA_l);
        // S6: gemmL2 || aggR2
        fused_step<H_DIM, H_DIM, H_DIM, H_DIM, H_DIM, 0>
            <<<GEMM_BLOCKS + N_NODES, 256, SMEM, stream>>>(
            bufA_l, W2, b2, dsi_l, bufH_l, N_NODES, GEMM_BLOCKS,
            bufH_r, dso_r, rp_r, col_r, bufA_r);
        // S7: gemmR2
        gemm_only_kernel<H_DIM, H_DIM><<<GEMM_BLOCKS, 256, SMEM, stream>>>(
            bufA_r, W2, b2, dsi_r, bufH_r, N_NODES);
        // S8: pools
        pool_kernel<<<(N_NODES + 63) / 64, 256, 0, stream>>>(bufH_l, gid_l, pool_l);
        pool_kernel<<<(N_NODES + 63) / 64, 256, 0, stream>>>(bufH_r, gid_r, pool_r);
    } else {
        // sequential fallback, shared big buffers
        const float* xs[2]  = { xl, xr };
        const float* dsos[2] = { dso_l, dso_r };
        const float* dsis[2] = { dsi_l, dsi_r };
        const int* rps[2]   = { rp_l, rp_r };
        const int* cols[2]  = { col_l, col_r };
        const int* gids[2]  = { gid_l, gid_r };
        float* pools[2]     = { pool_l, pool_r };
        for (int s = 0; s < 2; ++s) {
            agg_only_kernel<FIN_DIM, FIN_DIM, K0PAD, 1><<<N_NODES / 2, 256, 0, stream>>>(
                xs[s], dsos[s], rps[s], cols[s], bufA_l);
            gemm_only_kernel<K0PAD, FIN_DIM><<<GEMM_BLOCKS, 256, SMEM, stream>>>(
                bufA_l, W0, b0, dsis[s], bufH_l, N_NODES);
            agg_only_kernel<H_DIM, H_DIM, H_DIM, 0><<<N_NODES, 256, 0, stream>>>(
                bufH_l, dsos[s], rps[s], cols[s], bufA_l);
            gemm_only_kernel<H_DIM, H_DIM><<<GEMM_BLOCKS, 256, SMEM, stream>>>(
                bufA_l, W1, b1, dsis[s], bufH_l, N_NODES);
            agg_only_kernel<H_DIM, H_DIM, H_DIM, 0><<<N_NODES, 256, 0, stream>>>(
                bufH_l, dsos[s], rps[s], cols[s], bufA_l);
            gemm_only_kernel<H_DIM, H_DIM><<<GEMM_BLOCKS, 256, SMEM, stream>>>(
                bufA_l, W2, b2, dsis[s], bufH_l, N_NODES);
            pool_kernel<<<(N_NODES + 63) / 64, 256, 0, stream>>>(bufH_l, gids[s], pools[s]);
        }
    }

    mlp_kernel<<<N_GRAPHS, 256, 0, stream>>>(pool_l, pool_r, Wf1, bf1, Wf2, bf2, out);
}

// Round 4
// 1086.935 us; speedup vs baseline: 1.4100x; 1.4100x over previous
//
#include <hip/hip_runtime.h>

#define N_NODES 50000
#define N_EDGES 800000
#define N_GRAPHS 100
#define FIN_DIM 74
#define H_DIM 256
#define K0PAD 96
#define GEMM_BLOCKS 782   // 2 n-tiles * 391 m-tiles of 128
#define SCAN_BLOCKS 196   // ceil(50000/256)

typedef float f32x4 __attribute__((ext_vector_type(4)));
typedef float f32x2 __attribute__((ext_vector_type(2)));
typedef unsigned short us2 __attribute__((ext_vector_type(2)));
typedef unsigned short us4 __attribute__((ext_vector_type(4)));
typedef unsigned short us8 __attribute__((ext_vector_type(8)));
typedef __bf16 bf16x8 __attribute__((ext_vector_type(8)));

__device__ __forceinline__ unsigned short f2bf(float x) {
    unsigned u = __builtin_bit_cast(unsigned, x);
    u += 0x7fff + ((u >> 16) & 1);
    return (unsigned short)(u >> 16);
}
__device__ __forceinline__ float bf2f(unsigned short h) {
    return __builtin_bit_cast(float, (unsigned)h << 16);
}

// ---------------- CSR construction (both streams, grid.y selects) ----------------

__global__ void count_kernel(const int* __restrict__ src_a, const int* __restrict__ dst_a,
                             int* __restrict__ cs_a, int* __restrict__ cd_a,
                             const int* __restrict__ src_b, const int* __restrict__ dst_b,
                             int* __restrict__ cs_b, int* __restrict__ cd_b) {
    const int* src = blockIdx.y ? src_b : src_a;
    const int* dst = blockIdx.y ? dst_b : dst_a;
    int* cs = blockIdx.y ? cs_b : cs_a;
    int* cd = blockIdx.y ? cd_b : cd_a;
    int e = blockIdx.x * blockDim.x + threadIdx.x;
    if (e < N_EDGES) {
        atomicAdd(&cs[src[e]], 1);
        atomicAdd(&cd[dst[e]], 1);
    }
}

__global__ void rsqrt_deg_kernel(const int* __restrict__ cs_a, const int* __restrict__ cd_a,
                                 float* __restrict__ dso_a, float* __restrict__ dsi_a,
                                 const int* __restrict__ cs_b, const int* __restrict__ cd_b,
                                 float* __restrict__ dso_b, float* __restrict__ dsi_b) {
    const int* cs = blockIdx.y ? cs_b : cs_a;
    const int* cd = blockIdx.y ? cd_b : cd_a;
    float* dso = blockIdx.y ? dso_b : dso_a;
    float* dsi = blockIdx.y ? dsi_b : dsi_a;
    int i = blockIdx.x * blockDim.x + threadIdx.x;
    if (i < N_NODES) {
        dso[i] = rsqrtf(fmaxf((float)cs[i], 1.0f));
        dsi[i] = rsqrtf(fmaxf((float)cd[i], 1.0f));
    }
}

__device__ __forceinline__ int block_excl_scan(int v, int* wsums) {
    int lane = threadIdx.x & 63, w = threadIdx.x >> 6;
    int x = v;
    #pragma unroll
    for (int ofs = 1; ofs < 64; ofs <<= 1) {
        int y = __shfl_up(x, ofs, 64);
        if (lane >= ofs) x += y;
    }
    if (lane == 63) wsums[w] = x;
    __syncthreads();
    int wo = 0;
    #pragma unroll
    for (int k = 0; k < 4; ++k) if (k < w) wo += wsums[k];
    return wo + x - v;
}

__global__ void scan1_kernel(const int* __restrict__ cnt_a, int* __restrict__ rp_a, int* __restrict__ bs_a,
                             const int* __restrict__ cnt_b, int* __restrict__ rp_b, int* __restrict__ bs_b) {
    const int* cnt = blockIdx.y ? cnt_b : cnt_a;
    int* rp = blockIdx.y ? rp_b : rp_a;
    int* bs = blockIdx.y ? bs_b : bs_a;
    __shared__ int ws[4];
    int i = blockIdx.x * 256 + threadIdx.x;
    int v = (i < N_NODES) ? cnt[i] : 0;
    int ex = block_excl_scan(v, ws);
    if (i < N_NODES) rp[i] = ex;
    if (threadIdx.x == 255) bs[blockIdx.x] = ex + v;
}

__global__ void scan2_kernel(int* __restrict__ bs_a, int* __restrict__ bs_b, int nb) {
    int* bs = blockIdx.y ? bs_b : bs_a;
    __shared__ int ws[4];
    int i = threadIdx.x;
    int v = (i < nb) ? bs[i] : 0;
    int ex = block_excl_scan(v, ws);
    __syncthreads();
    if (i < nb) bs[i] = ex;
}

__global__ void scan3_kernel(int* __restrict__ rp_a, const int* __restrict__ bs_a,
                             int* __restrict__ rp_b, const int* __restrict__ bs_b) {
    int* rp = blockIdx.y ? rp_b : rp_a;
    const int* bs = blockIdx.y ? bs_b : bs_a;
    int i = blockIdx.x * 256 + threadIdx.x;
    if (i < N_NODES) rp[i] += bs[blockIdx.x];
    if (i == 0) rp[N_NODES] = N_EDGES;
}

__global__ void fill_kernel(const int* __restrict__ src_a, const int* __restrict__ dst_a,
                            const int* __restrict__ rp_a, int* __restrict__ fc_a, int* __restrict__ col_a,
                            const int* __restrict__ src_b, const int* __restrict__ dst_b,
                            const int* __restrict__ rp_b, int* __restrict__ fc_b, int* __restrict__ col_b) {
    const int* src = blockIdx.y ? src_b : src_a;
    const int* dst = blockIdx.y ? dst_b : dst_a;
    const int* rp  = blockIdx.y ? rp_b : rp_a;
    int* fc  = blockIdx.y ? fc_b : fc_a;
    int* col = blockIdx.y ? col_b : col_a;
    int e = blockIdx.x * blockDim.x + threadIdx.x;
    if (e < N_EDGES) {
        int d = dst[e];
        int p = atomicAdd(&fc[d], 1);
        col[rp[d] + p] = src[e];
    }
}

// ---------------- layer-0 aggregation (f32 input, 74 -> pad 96) ----------------
// 2 nodes per 256-thread block, 128 threads each.

__global__ void agg_f32_kernel(const float* __restrict__ h, const float* __restrict__ dso,
                               const int* __restrict__ rp, const int* __restrict__ col,
                               float* __restrict__ A) {
    int n = blockIdx.x * 2 + (threadIdx.x >> 7);
    int f = threadIdx.x & 127;
    int beg = rp[n], end = rp[n + 1];
    if (f < FIN_DIM) {
        float acc0 = 0.f, acc1 = 0.f;
        int j = beg;
        for (; j + 3 < end; j += 4) {
            int s0 = col[j], s1 = col[j + 1], s2 = col[j + 2], s3 = col[j + 3];
            float d0 = dso[s0], d1 = dso[s1], d2 = dso[s2], d3 = dso[s3];
            float h0 = h[(size_t)s0 * FIN_DIM + f];
            float h1 = h[(size_t)s1 * FIN_DIM + f];
            float h2 = h[(size_t)s2 * FIN_DIM + f];
            float h3 = h[(size_t)s3 * FIN_DIM + f];
            acc0 += h0 * d0 + h1 * d1;
            acc1 += h2 * d2 + h3 * d3;
        }
        for (; j < end; ++j) {
            int s = col[j];
            acc0 += h[(size_t)s * FIN_DIM + f] * dso[s];
        }
        A[(size_t)n * K0PAD + f] = acc0 + acc1;
    } else if (f < K0PAD) {
        A[(size_t)n * K0PAD + f] = 0.0f;
    }
}

// ---------------- hidden-layer aggregation (bf16 input, 256 wide) ----------------
// 2 nodes per 256-thread block; each thread owns 2 feature cols via one us2 load.

__global__ void agg_bf16_kernel(const unsigned short* __restrict__ h, const float* __restrict__ dso,
                                const int* __restrict__ rp, const int* __restrict__ col,
                                float* __restrict__ A) {
    int n = blockIdx.x * 2 + (threadIdx.x >> 7);
    int f2 = (threadIdx.x & 127) * 2;
    int beg = rp[n], end = rp[n + 1];
    float a0 = 0.f, a1 = 0.f, b0 = 0.f, b1 = 0.f;
    int j = beg;
    for (; j + 3 < end; j += 4) {
        int s0 = col[j], s1 = col[j + 1], s2 = col[j + 2], s3 = col[j + 3];
        float d0 = dso[s0], d1 = dso[s1], d2 = dso[s2], d3 = dso[s3];
        us2 v0 = *(const us2*)&h[(size_t)s0 * H_DIM + f2];
        us2 v1 = *(const us2*)&h[(size_t)s1 * H_DIM + f2];
        us2 v2 = *(const us2*)&h[(size_t)s2 * H_DIM + f2];
        us2 v3 = *(const us2*)&h[(size_t)s3 * H_DIM + f2];
        a0 += bf2f(v0[0]) * d0 + bf2f(v1[0]) * d1;
        a1 += bf2f(v0[1]) * d0 + bf2f(v1[1]) * d1;
        b0 += bf2f(v2[0]) * d2 + bf2f(v3[0]) * d3;
        b1 += bf2f(v2[1]) * d2 + bf2f(v3[1]) * d3;
    }
    for (; j < end; ++j) {
        int s = col[j];
        float d = dso[s];
        us2 v = *(const us2*)&h[(size_t)s * H_DIM + f2];
        a0 += bf2f(v[0]) * d;
        a1 += bf2f(v[1]) * d;
    }
    f32x2 r = { a0 + b0, a1 + b1 };
    *(f32x2*)&A[(size_t)n * H_DIM + f2] = r;
}

// ---------------- MFMA GEMM: h[m][j] = bf16(relu((A@W)[m][j]*dsi[m] + bias[j])) ----------------
// A: [M x K] f32, W: [KW x 256] f32, C: [M x 256] bf16 (ushort).
// Split precision: A = Ah + Al, W = Wh + Wl; acc += Al*Wh + Ah*Wl + Ah*Wh.

template<int K, int KW>
__global__ __launch_bounds__(256, 2) void gemm_mfma(
        const float* __restrict__ A, const float* __restrict__ W,
        const float* __restrict__ bias, const float* __restrict__ dsi,
        unsigned short* __restrict__ C, int M) {
    __shared__ unsigned short Ah[128][32];
    __shared__ unsigned short Al[128][32];
    __shared__ unsigned short Bh[128][36];
    __shared__ unsigned short Bl[128][36];

    int tid = threadIdx.x;
    int lane = tid & 63, wid = tid >> 6;
    int wm = (wid >> 1) * 64, wn = (wid & 1) * 64;
    int bm = blockIdx.y * 128, bn = blockIdx.x * 128;

    f32x4 acc[4][4] = {};

    int r0 = wm + (lane & 15);
    int c0 = wn + (lane & 15);
    int kA = (lane >> 4) * 8;

    for (int k0 = 0; k0 < K; k0 += 32) {
        #pragma unroll
        for (int i = 0; i < 4; ++i) {
            int q = tid + i * 256;
            int row = q >> 3, k4 = (q & 7) * 4;
            int gm = bm + row;
            f32x4 v = {0.f, 0.f, 0.f, 0.f};
            if (gm < M) v = *(const f32x4*)(A + (size_t)gm * K + k0 + k4);
            us4 h, l;
            #pragma unroll
            for (int j = 0; j < 4; ++j) {
                unsigned short hh = f2bf(v[j]);
                h[j] = hh;
                l[j] = f2bf(v[j] - bf2f(hh));
            }
            *(us4*)&Ah[row][k4] = h;
            *(us4*)&Al[row][k4] = l;
        }
        {
            int col = tid & 127, kg = tid >> 7;
            us4 h[4], l[4];
            #pragma unroll
            for (int g = 0; g < 4; ++g) {
                #pragma unroll
                for (int j = 0; j < 4; ++j) {
                    int gk = k0 + kg * 16 + g * 4 + j;
                    float w = 0.f;
                    if (gk < KW) w = W[(size_t)gk * H_DIM + bn + col];
                    unsigned short hh = f2bf(w);
                    h[g][j] = hh;
                    l[g][j] = f2bf(w - bf2f(hh));
                }
            }
            #pragma unroll
            for (int g = 0; g < 4; ++g) {
                *(us4*)&Bh[col][kg * 16 + g * 4] = h[g];
                *(us4*)&Bl[col][kg * 16 + g * 4] = l[g];
            }
        }
        __syncthreads();

        bf16x8 ah[4], al[4], bh[4], bl[4];
        #pragma unroll
        for (int m = 0; m < 4; ++m) {
            ah[m] = __builtin_bit_cast(bf16x8, *(const us8*)&Ah[r0 + m * 16][kA]);
            al[m] = __builtin_bit_cast(bf16x8, *(const us8*)&Al[r0 + m * 16][kA]);
        }
        #pragma unroll
        for (int n = 0; n < 4; ++n) {
            us4 x0 = *(const us4*)&Bh[c0 + n * 16][kA];
            us4 x1 = *(const us4*)&Bh[c0 + n * 16][kA + 4];
            us8 x;
            x[0] = x0[0]; x[1] = x0[1]; x[2] = x0[2]; x[3] = x0[3];
            x[4] = x1[0]; x[5] = x1[1]; x[6] = x1[2]; x[7] = x1[3];
            bh[n] = __builtin_bit_cast(bf16x8, x);
            us4 y0 = *(const us4*)&Bl[c0 + n * 16][kA];
            us4 y1 = *(const us4*)&Bl[c0 + n * 16][kA + 4];
            us8 y;
            y[0] = y0[0]; y[1] = y0[1]; y[2] = y0[2]; y[3] = y0[3];
            y[4] = y1[0]; y[5] = y1[1]; y[6] = y1[2]; y[7] = y1[3];
            bl[n] = __builtin_bit_cast(bf16x8, y);
        }

        #pragma unroll
        for (int m = 0; m < 4; ++m)
            #pragma unroll
            for (int n = 0; n < 4; ++n) {
                acc[m][n] = __builtin_amdgcn_mfma_f32_16x16x32_bf16(al[m], bh[n], acc[m][n], 0, 0, 0);
                acc[m][n] = __builtin_amdgcn_mfma_f32_16x16x32_bf16(ah[m], bl[n], acc[m][n], 0, 0, 0);
                acc[m][n] = __builtin_amdgcn_mfma_f32_16x16x32_bf16(ah[m], bh[n], acc[m][n], 0, 0, 0);
            }
        __syncthreads();
    }

    int rowq = (lane >> 4) * 4;
    #pragma unroll
    for (int n = 0; n < 4; ++n) {
        int gn = bn + wn + n * 16 + (lane & 15);
        float bv = bias[gn];
        #pragma unroll
        for (int m = 0; m < 4; ++m) {
            #pragma unroll
            for (int j = 0; j < 4; ++j) {
                int gm = bm + wm + m * 16 + rowq + j;
                if (gm < M) {
                    C[(size_t)gm * H_DIM + gn] = f2bf(fmaxf(acc[m][n][j] * dsi[gm] + bv, 0.0f));
                }
            }
        }
    }
}

// ---------------- pooling (bf16 input) ----------------

__global__ void pool_kernel(const unsigned short* __restrict__ h, const int* __restrict__ gid,
                            float* __restrict__ pool) {
    int n0 = blockIdx.x * 64;
    int f = threadIdx.x;
    int end = min(n0 + 64, N_NODES);
    float acc = 0.0f;
    int gcur = gid[n0];
    for (int i = n0; i < end; ++i) {
        int g = gid[i];
        if (g != gcur) {
            atomicAdd(&pool[(size_t)gcur * H_DIM + f], acc);
            acc = 0.0f;
            gcur = g;
        }
        acc += bf2f(h[(size_t)i * H_DIM + f]);
    }
    atomicAdd(&pool[(size_t)gcur * H_DIM + f], acc);
}

// ---------------- final MLP ----------------

__global__ __launch_bounds__(256) void mlp_kernel(
        const float* __restrict__ pl, const float* __restrict__ pr,
        const float* __restrict__ Wf1, const float* __restrict__ bf1,
        const float* __restrict__ Wf2, const float* __restrict__ bf2,
        float* __restrict__ out) {
    __shared__ float z[512];
    __shared__ float red[256];
    int g = blockIdx.x, tid = threadIdx.x;
    z[tid] = pl[(size_t)g * H_DIM + tid];
    z[tid + 256] = pr[(size_t)g * H_DIM + tid];
    __syncthreads();
    float t = bf1[tid];
    #pragma unroll 8
    for (int k = 0; k < 512; ++k) t += z[k] * Wf1[(size_t)k * H_DIM + tid];
    t = fmaxf(t, 0.0f);
    red[tid] = t * Wf2[tid];
    __syncthreads();
    for (int ofs = 128; ofs > 0; ofs >>= 1) {
        if (tid < ofs) red[tid] += red[tid + ofs];
        __syncthreads();
    }
    if (tid == 0) out[g] = red[0] + bf2[0];
}

// ---------------- driver ----------------

extern "C" void kernel_launch(void* const* d_in, const int* in_sizes, int n_in,
                              void* d_out, int out_size, void* d_ws, size_t ws_size,
                              hipStream_t stream) {
    const float* xl   = (const float*)d_in[0];
    const float* xr   = (const float*)d_in[1];
    const int* src_l  = (const int*)d_in[2];
    const int* dst_l  = (const int*)d_in[3];
    const int* src_r  = (const int*)d_in[4];
    const int* dst_r  = (const int*)d_in[5];
    const int* gid_l  = (const int*)d_in[6];
    const int* gid_r  = (const int*)d_in[7];
    const float* W0   = (const float*)d_in[8];
    const float* b0   = (const float*)d_in[9];
    const float* W1   = (const float*)d_in[10];
    const float* b1   = (const float*)d_in[11];
    const float* W2   = (const float*)d_in[12];
    const float* b2   = (const float*)d_in[13];
    const float* Wf1  = (const float*)d_in[14];
    const float* bf1  = (const float*)d_in[15];
    const float* Wf2  = (const float*)d_in[16];
    const float* bf2  = (const float*)d_in[17];
    float* out = (float*)d_out;
    (void)in_sizes; (void)n_in; (void)out_size; (void)ws_size;

    size_t off = 0;
    auto carve = [&](size_t bytes) {
        void* p = (char*)d_ws + off;
        off += (bytes + 255) & ~(size_t)255;
        return p;
    };
    const size_t NB4 = (size_t)N_NODES * 4;

    // --- zero zone (one memset covers all) ---
    char* zstart = (char*)d_ws;
    int*   cnt_s_l = (int*)carve(NB4);
    int*   cnt_d_l = (int*)carve(NB4);
    int*   fillc_l = (int*)carve(NB4);
    int*   cnt_s_r = (int*)carve(NB4);
    int*   cnt_d_r = (int*)carve(NB4);
    int*   fillc_r = (int*)carve(NB4);
    float* pool_l  = (float*)carve((size_t)N_GRAPHS * H_DIM * 4);
    float* pool_r  = (float*)carve((size_t)N_GRAPHS * H_DIM * 4);
    size_t zbytes = off;

    float* dso_l = (float*)carve(NB4);
    float* dsi_l = (float*)carve(NB4);
    float* dso_r = (float*)carve(NB4);
    float* dsi_r = (float*)carve(NB4);
    int*   rp_l  = (int*)carve((size_t)(N_NODES + 1) * 4);
    int*   rp_r  = (int*)carve((size_t)(N_NODES + 1) * 4);
    int*   col_l = (int*)carve((size_t)N_EDGES * 4);
    int*   col_r = (int*)carve((size_t)N_EDGES * 4);
    int*   bs_l  = (int*)carve((size_t)SCAN_BLOCKS * 4);
    int*   bs_r  = (int*)carve((size_t)SCAN_BLOCKS * 4);

    float*          bufA = (float*)carve((size_t)N_NODES * H_DIM * 4);          // agg out (f32)
    unsigned short* bufH = (unsigned short*)carve((size_t)N_NODES * H_DIM * 2); // layer out (bf16)

    hipMemsetAsync(zstart, 0, zbytes, stream);

    const int EB = 256, EG = (N_EDGES + EB - 1) / EB;
    const int NG = (N_NODES + 255) / 256;
    dim3 ggrid(H_DIM / 128, (N_NODES + 127) / 128);

    // --- CSR for both streams ---
    count_kernel<<<dim3(EG, 2), EB, 0, stream>>>(src_l, dst_l, cnt_s_l, cnt_d_l,
                                                 src_r, dst_r, cnt_s_r, cnt_d_r);
    rsqrt_deg_kernel<<<dim3(NG, 2), 256, 0, stream>>>(cnt_s_l, cnt_d_l, dso_l, dsi_l,
                                                      cnt_s_r, cnt_d_r, dso_r, dsi_r);
    scan1_kernel<<<dim3(SCAN_BLOCKS, 2), 256, 0, stream>>>(cnt_d_l, rp_l, bs_l, cnt_d_r, rp_r, bs_r);
    scan2_kernel<<<dim3(1, 2), 256, 0, stream>>>(bs_l, bs_r, SCAN_BLOCKS);
    scan3_kernel<<<dim3(SCAN_BLOCKS, 2), 256, 0, stream>>>(rp_l, bs_l, rp_r, bs_r);
    fill_kernel<<<dim3(EG, 2), EB, 0, stream>>>(src_l, dst_l, rp_l, fillc_l, col_l,
                                                src_r, dst_r, rp_r, fillc_r, col_r);

    const float* xs[2]   = { xl, xr };
    const float* dsos[2] = { dso_l, dso_r };
    const float* dsis[2] = { dsi_l, dsi_r };
    const int* rps[2]    = { rp_l, rp_r };
    const int* cols[2]   = { col_l, col_r };
    const int* gids[2]   = { gid_l, gid_r };
    float* pools[2]      = { pool_l, pool_r };

    for (int s = 0; s < 2; ++s) {
        // layer 0: f32 gather (74 -> pad 96), GEMM K=96 -> bf16 h
        agg_f32_kernel<<<N_NODES / 2, 256, 0, stream>>>(xs[s], dsos[s], rps[s], cols[s], bufA);
        gemm_mfma<K0PAD, FIN_DIM><<<ggrid, 256, 0, stream>>>(bufA, W0, b0, dsis[s], bufH, N_NODES);
        // layer 1: bf16 gather, GEMM K=256
        agg_bf16_kernel<<<N_NODES / 2, 256, 0, stream>>>(bufH, dsos[s], rps[s], cols[s], bufA);
        gemm_mfma<H_DIM, H_DIM><<<ggrid, 256, 0, stream>>>(bufA, W1, b1, dsis[s], bufH, N_NODES);
        // layer 2
        agg_bf16_kernel<<<N_NODES / 2, 256, 0, stream>>>(bufH, dsos[s], rps[s], cols[s], bufA);
        gemm_mfma<H_DIM, H_DIM><<<ggrid, 256, 0, stream>>>(bufA, W2, b2, dsis[s], bufH, N_NODES);

        pool_kernel<<<(N_NODES + 63) / 64, 256, 0, stream>>>(bufH, gids[s], pools[s]);
    }

    mlp_kernel<<<N_GRAPHS, 256, 0, stream>>>(pool_l, pool_r, Wf1, bf1, Wf2, bf2, out);
}

// Round 5
// 1030.361 us; speedup vs baseline: 1.4874x; 1.0549x over previous
//
#include <hip/hip_runtime.h>

#define N_NODES 50000
#define N_EDGES 800000
#define N_GRAPHS 100
#define FIN_DIM 74
#define H_DIM 256
#define K0PAD 96
#define NCOPY 8
#define SCAN_BLOCKS 196   // ceil(50000/256)

typedef float f32x4 __attribute__((ext_vector_type(4)));
typedef float f32x2 __attribute__((ext_vector_type(2)));
typedef unsigned short us2 __attribute__((ext_vector_type(2)));
typedef unsigned short us4 __attribute__((ext_vector_type(4)));
typedef unsigned short us8 __attribute__((ext_vector_type(8)));
typedef __bf16 bf16x8 __attribute__((ext_vector_type(8)));

__device__ __forceinline__ unsigned short f2bf(float x) {
    unsigned u = __builtin_bit_cast(unsigned, x);
    u += 0x7fff + ((u >> 16) & 1);
    return (unsigned short)(u >> 16);
}
__device__ __forceinline__ float bf2f(unsigned short h) {
    return __builtin_bit_cast(float, (unsigned)h << 16);
}

// ---------------- CSR construction ----------------
// hist: 8-way privatized histograms (copy = blockIdx.x & 7 -> XCD-local L2 lines)
// + per-edge rank within its copy (enables atomic-free scatter).

__global__ void hist_kernel(const int* __restrict__ src_a, const int* __restrict__ dst_a,
                            int* __restrict__ csK_a, int* __restrict__ fcK_a, int* __restrict__ r_a,
                            const int* __restrict__ src_b, const int* __restrict__ dst_b,
                            int* __restrict__ csK_b, int* __restrict__ fcK_b, int* __restrict__ r_b) {
    const int* src = blockIdx.y ? src_b : src_a;
    const int* dst = blockIdx.y ? dst_b : dst_a;
    int* csK = blockIdx.y ? csK_b : csK_a;
    int* fcK = blockIdx.y ? fcK_b : fcK_a;
    int* r   = blockIdx.y ? r_b   : r_a;
    int e = blockIdx.x * blockDim.x + threadIdx.x;
    if (e < N_EDGES) {
        int k = blockIdx.x & (NCOPY - 1);
        int d = dst[e], s = src[e];
        r[e] = atomicAdd(&fcK[k * N_NODES + d], 1);
        atomicAdd(&csK[k * N_NODES + s], 1);
    }
}

// per node: sum out-deg copies -> dso; exclusive prefix of dst copies -> bases (+cnt_d, dsi)
__global__ void deg_base_kernel(int* __restrict__ csK_a, int* __restrict__ fcK_a,
                                float* __restrict__ dso_a, float* __restrict__ dsi_a,
                                int* __restrict__ cnt_a,
                                int* __restrict__ csK_b, int* __restrict__ fcK_b,
                                float* __restrict__ dso_b, float* __restrict__ dsi_b,
                                int* __restrict__ cnt_b) {
    int* csK = blockIdx.y ? csK_b : csK_a;
    int* fcK = blockIdx.y ? fcK_b : fcK_a;
    float* dso = blockIdx.y ? dso_b : dso_a;
    float* dsi = blockIdx.y ? dsi_b : dsi_a;
    int* cnt = blockIdx.y ? cnt_b : cnt_a;
    int i = blockIdx.x * blockDim.x + threadIdx.x;
    if (i < N_NODES) {
        int cs = 0;
        #pragma unroll
        for (int k = 0; k < NCOPY; ++k) cs += csK[k * N_NODES + i];
        dso[i] = rsqrtf(fmaxf((float)cs, 1.0f));
        int b = 0;
        #pragma unroll
        for (int k = 0; k < NCOPY; ++k) {
            int t = fcK[k * N_NODES + i];
            fcK[k * N_NODES + i] = b;
            b += t;
        }
        cnt[i] = b;
        dsi[i] = rsqrtf(fmaxf((float)b, 1.0f));
    }
}

__device__ __forceinline__ int block_excl_scan(int v, int* wsums) {
    int lane = threadIdx.x & 63, w = threadIdx.x >> 6;
    int x = v;
    #pragma unroll
    for (int ofs = 1; ofs < 64; ofs <<= 1) {
        int y = __shfl_up(x, ofs, 64);
        if (lane >= ofs) x += y;
    }
    if (lane == 63) wsums[w] = x;
    __syncthreads();
    int wo = 0;
    #pragma unroll
    for (int k = 0; k < 4; ++k) if (k < w) wo += wsums[k];
    return wo + x - v;
}

__global__ void scan1_kernel(const int* __restrict__ cnt_a, int* __restrict__ rp_a, int* __restrict__ bs_a,
                             const int* __restrict__ cnt_b, int* __restrict__ rp_b, int* __restrict__ bs_b) {
    const int* cnt = blockIdx.y ? cnt_b : cnt_a;
    int* rp = blockIdx.y ? rp_b : rp_a;
    int* bs = blockIdx.y ? bs_b : bs_a;
    __shared__ int ws[4];
    int i = blockIdx.x * 256 + threadIdx.x;
    int v = (i < N_NODES) ? cnt[i] : 0;
    int ex = block_excl_scan(v, ws);
    if (i < N_NODES) rp[i] = ex;
    if (threadIdx.x == 255) bs[blockIdx.x] = ex + v;
}

__global__ void scan2_kernel(int* __restrict__ bs_a, int* __restrict__ bs_b, int nb) {
    int* bs = blockIdx.y ? bs_b : bs_a;
    __shared__ int ws[4];
    int i = threadIdx.x;
    int v = (i < nb) ? bs[i] : 0;
    int ex = block_excl_scan(v, ws);
    __syncthreads();
    if (i < nb) bs[i] = ex;
}

__global__ void scan3_kernel(int* __restrict__ rp_a, const int* __restrict__ bs_a,
                             int* __restrict__ rp_b, const int* __restrict__ bs_b) {
    int* rp = blockIdx.y ? rp_b : rp_a;
    const int* bs = blockIdx.y ? bs_b : bs_a;
    int i = blockIdx.x * 256 + threadIdx.x;
    if (i < N_NODES) rp[i] += bs[blockIdx.x];
    if (i == 0) rp[N_NODES] = N_EDGES;
}

// atomic-free scatter: col[rp[d] + base_k[d] + r[e]] = src[e]
__global__ void scatter_kernel(const int* __restrict__ src_a, const int* __restrict__ dst_a,
                               const int* __restrict__ rp_a, const int* __restrict__ fcK_a,
                               const int* __restrict__ r_a, int* __restrict__ col_a,
                               const int* __restrict__ src_b, const int* __restrict__ dst_b,
                               const int* __restrict__ rp_b, const int* __restrict__ fcK_b,
                               const int* __restrict__ r_b, int* __restrict__ col_b) {
    const int* src = blockIdx.y ? src_b : src_a;
    const int* dst = blockIdx.y ? dst_b : dst_a;
    const int* rp  = blockIdx.y ? rp_b : rp_a;
    const int* fcK = blockIdx.y ? fcK_b : fcK_a;
    const int* r   = blockIdx.y ? r_b : r_a;
    int* col = blockIdx.y ? col_b : col_a;
    int e = blockIdx.x * blockDim.x + threadIdx.x;
    if (e < N_EDGES) {
        int k = blockIdx.x & (NCOPY - 1);
        int d = dst[e];
        col[rp[d] + fcK[k * N_NODES + d] + r[e]] = src[e];
    }
}

// ---------------- layer-0 aggregation (f32 input, 74 -> pad 96) ----------------

__global__ void agg_f32_kernel(const float* __restrict__ h, const float* __restrict__ dso,
                               const int* __restrict__ rp, const int* __restrict__ col,
                               float* __restrict__ A) {
    int n = blockIdx.x * 2 + (threadIdx.x >> 7);
    int f = threadIdx.x & 127;
    int beg = rp[n], end = rp[n + 1];
    if (f < FIN_DIM) {
        float acc0 = 0.f, acc1 = 0.f;
        int j = beg;
        for (; j + 3 < end; j += 4) {
            int s0 = col[j], s1 = col[j + 1], s2 = col[j + 2], s3 = col[j + 3];
            float d0 = dso[s0], d1 = dso[s1], d2 = dso[s2], d3 = dso[s3];
            float h0 = h[(size_t)s0 * FIN_DIM + f];
            float h1 = h[(size_t)s1 * FIN_DIM + f];
            float h2 = h[(size_t)s2 * FIN_DIM + f];
            float h3 = h[(size_t)s3 * FIN_DIM + f];
            acc0 += h0 * d0 + h1 * d1;
            acc1 += h2 * d2 + h3 * d3;
        }
        for (; j < end; ++j) {
            int s = col[j];
            acc0 += h[(size_t)s * FIN_DIM + f] * dso[s];
        }
        A[(size_t)n * K0PAD + f] = acc0 + acc1;
    } else if (f < K0PAD) {
        A[(size_t)n * K0PAD + f] = 0.0f;
    }
}

// ---------------- hidden-layer aggregation (bf16 input, 256 wide) ----------------

__global__ void agg_bf16_kernel(const unsigned short* __restrict__ h, const float* __restrict__ dso,
                                const int* __restrict__ rp, const int* __restrict__ col,
                                float* __restrict__ A) {
    int n = blockIdx.x * 2 + (threadIdx.x >> 7);
    int f2 = (threadIdx.x & 127) * 2;
    int beg = rp[n], end = rp[n + 1];
    float a0 = 0.f, a1 = 0.f, b0 = 0.f, b1 = 0.f;
    int j = beg;
    for (; j + 3 < end; j += 4) {
        int s0 = col[j], s1 = col[j + 1], s2 = col[j + 2], s3 = col[j + 3];
        float d0 = dso[s0], d1 = dso[s1], d2 = dso[s2], d3 = dso[s3];
        us2 v0 = *(const us2*)&h[(size_t)s0 * H_DIM + f2];
        us2 v1 = *(const us2*)&h[(size_t)s1 * H_DIM + f2];
        us2 v2 = *(const us2*)&h[(size_t)s2 * H_DIM + f2];
        us2 v3 = *(const us2*)&h[(size_t)s3 * H_DIM + f2];
        a0 += bf2f(v0[0]) * d0 + bf2f(v1[0]) * d1;
        a1 += bf2f(v0[1]) * d0 + bf2f(v1[1]) * d1;
        b0 += bf2f(v2[0]) * d2 + bf2f(v3[0]) * d3;
        b1 += bf2f(v2[1]) * d2 + bf2f(v3[1]) * d3;
    }
    for (; j < end; ++j) {
        int s = col[j];
        float d = dso[s];
        us2 v = *(const us2*)&h[(size_t)s * H_DIM + f2];
        a0 += bf2f(v[0]) * d;
        a1 += bf2f(v[1]) * d;
    }
    f32x2 r = { a0 + b0, a1 + b1 };
    *(f32x2*)&A[(size_t)n * H_DIM + f2] = r;
}

// ---------------- MFMA GEMM: h[m][j] = bf16(relu((A@W)[m][j]*dsi[m] + bias[j])) ----------------

template<int K, int KW>
__global__ __launch_bounds__(256, 2) void gemm_mfma(
        const float* __restrict__ A, const float* __restrict__ W,
        const float* __restrict__ bias, const float* __restrict__ dsi,
        unsigned short* __restrict__ C, int M) {
    __shared__ unsigned short Ah[128][32];
    __shared__ unsigned short Al[128][32];
    __shared__ unsigned short Bh[128][36];
    __shared__ unsigned short Bl[128][36];

    int tid = threadIdx.x;
    int lane = tid & 63, wid = tid >> 6;
    int wm = (wid >> 1) * 64, wn = (wid & 1) * 64;
    int bm = blockIdx.y * 128, bn = blockIdx.x * 128;

    f32x4 acc[4][4] = {};

    int r0 = wm + (lane & 15);
    int c0 = wn + (lane & 15);
    int kA = (lane >> 4) * 8;

    for (int k0 = 0; k0 < K; k0 += 32) {
        #pragma unroll
        for (int i = 0; i < 4; ++i) {
            int q = tid + i * 256;
            int row = q >> 3, k4 = (q & 7) * 4;
            int gm = bm + row;
            f32x4 v = {0.f, 0.f, 0.f, 0.f};
            if (gm < M) v = *(const f32x4*)(A + (size_t)gm * K + k0 + k4);
            us4 h, l;
            #pragma unroll
            for (int j = 0; j < 4; ++j) {
                unsigned short hh = f2bf(v[j]);
                h[j] = hh;
                l[j] = f2bf(v[j] - bf2f(hh));
            }
            *(us4*)&Ah[row][k4] = h;
            *(us4*)&Al[row][k4] = l;
        }
        {
            int col = tid & 127, kg = tid >> 7;
            us4 h[4], l[4];
            #pragma unroll
            for (int g = 0; g < 4; ++g) {
                #pragma unroll
                for (int j = 0; j < 4; ++j) {
                    int gk = k0 + kg * 16 + g * 4 + j;
                    float w = 0.f;
                    if (gk < KW) w = W[(size_t)gk * H_DIM + bn + col];
                    unsigned short hh = f2bf(w);
                    h[g][j] = hh;
                    l[g][j] = f2bf(w - bf2f(hh));
                }
            }
            #pragma unroll
            for (int g = 0; g < 4; ++g) {
                *(us4*)&Bh[col][kg * 16 + g * 4] = h[g];
                *(us4*)&Bl[col][kg * 16 + g * 4] = l[g];
            }
        }
        __syncthreads();

        bf16x8 ah[4], al[4], bh[4], bl[4];
        #pragma unroll
        for (int m = 0; m < 4; ++m) {
            ah[m] = __builtin_bit_cast(bf16x8, *(const us8*)&Ah[r0 + m * 16][kA]);
            al[m] = __builtin_bit_cast(bf16x8, *(const us8*)&Al[r0 + m * 16][kA]);
        }
        #pragma unroll
        for (int n = 0; n < 4; ++n) {
            us4 x0 = *(const us4*)&Bh[c0 + n * 16][kA];
            us4 x1 = *(const us4*)&Bh[c0 + n * 16][kA + 4];
            us8 x;
            x[0] = x0[0]; x[1] = x0[1]; x[2] = x0[2]; x[3] = x0[3];
            x[4] = x1[0]; x[5] = x1[1]; x[6] = x1[2]; x[7] = x1[3];
            bh[n] = __builtin_bit_cast(bf16x8, x);
            us4 y0 = *(const us4*)&Bl[c0 + n * 16][kA];
            us4 y1 = *(const us4*)&Bl[c0 + n * 16][kA + 4];
            us8 y;
            y[0] = y0[0]; y[1] = y0[1]; y[2] = y0[2]; y[3] = y0[3];
            y[4] = y1[0]; y[5] = y1[1]; y[6] = y1[2]; y[7] = y1[3];
            bl[n] = __builtin_bit_cast(bf16x8, y);
        }

        #pragma unroll
        for (int m = 0; m < 4; ++m)
            #pragma unroll
            for (int n = 0; n < 4; ++n) {
                acc[m][n] = __builtin_amdgcn_mfma_f32_16x16x32_bf16(al[m], bh[n], acc[m][n], 0, 0, 0);
                acc[m][n] = __builtin_amdgcn_mfma_f32_16x16x32_bf16(ah[m], bl[n], acc[m][n], 0, 0, 0);
                acc[m][n] = __builtin_amdgcn_mfma_f32_16x16x32_bf16(ah[m], bh[n], acc[m][n], 0, 0, 0);
            }
        __syncthreads();
    }

    int rowq = (lane >> 4) * 4;
    #pragma unroll
    for (int n = 0; n < 4; ++n) {
        int gn = bn + wn + n * 16 + (lane & 15);
        float bv = bias[gn];
        #pragma unroll
        for (int m = 0; m < 4; ++m) {
            #pragma unroll
            for (int j = 0; j < 4; ++j) {
                int gm = bm + wm + m * 16 + rowq + j;
                if (gm < M) {
                    C[(size_t)gm * H_DIM + gn] = f2bf(fmaxf(acc[m][n][j] * dsi[gm] + bv, 0.0f));
                }
            }
        }
    }
}

// ---------------- pooling (bf16 input) ----------------

__global__ void pool_kernel(const unsigned short* __restrict__ h, const int* __restrict__ gid,
                            float* __restrict__ pool) {
    int n0 = blockIdx.x * 64;
    int f = threadIdx.x;
    int end = min(n0 + 64, N_NODES);
    float acc = 0.0f;
    int gcur = gid[n0];
    for (int i = n0; i < end; ++i) {
        int g = gid[i];
        if (g != gcur) {
            atomicAdd(&pool[(size_t)gcur * H_DIM + f], acc);
            acc = 0.0f;
            gcur = g;
        }
        acc += bf2f(h[(size_t)i * H_DIM + f]);
    }
    atomicAdd(&pool[(size_t)gcur * H_DIM + f], acc);
}

// ---------------- final MLP ----------------

__global__ __launch_bounds__(256) void mlp_kernel(
        const float* __restrict__ pl, const float* __restrict__ pr,
        const float* __restrict__ Wf1, const float* __restrict__ bf1,
        const float* __restrict__ Wf2, const float* __restrict__ bf2,
        float* __restrict__ out) {
    __shared__ float z[512];
    __shared__ float red[256];
    int g = blockIdx.x, tid = threadIdx.x;
    z[tid] = pl[(size_t)g * H_DIM + tid];
    z[tid + 256] = pr[(size_t)g * H_DIM + tid];
    __syncthreads();
    float t = bf1[tid];
    #pragma unroll 8
    for (int k = 0; k < 512; ++k) t += z[k] * Wf1[(size_t)k * H_DIM + tid];
    t = fmaxf(t, 0.0f);
    red[tid] = t * Wf2[tid];
    __syncthreads();
    for (int ofs = 128; ofs > 0; ofs >>= 1) {
        if (tid < ofs) red[tid] += red[tid + ofs];
        __syncthreads();
    }
    if (tid == 0) out[g] = red[0] + bf2[0];
}

// ---------------- driver ----------------

extern "C" void kernel_launch(void* const* d_in, const int* in_sizes, int n_in,
                              void* d_out, int out_size, void* d_ws, size_t ws_size,
                              hipStream_t stream) {
    const float* xl   = (const float*)d_in[0];
    const float* xr   = (const float*)d_in[1];
    const int* src_l  = (const int*)d_in[2];
    const int* dst_l  = (const int*)d_in[3];
    const int* src_r  = (const int*)d_in[4];
    const int* dst_r  = (const int*)d_in[5];
    const int* gid_l  = (const int*)d_in[6];
    const int* gid_r  = (const int*)d_in[7];
    const float* W0   = (const float*)d_in[8];
    const float* b0   = (const float*)d_in[9];
    const float* W1   = (const float*)d_in[10];
    const float* b1   = (const float*)d_in[11];
    const float* W2   = (const float*)d_in[12];
    const float* b2   = (const float*)d_in[13];
    const float* Wf1  = (const float*)d_in[14];
    const float* bf1  = (const float*)d_in[15];
    const float* Wf2  = (const float*)d_in[16];
    const float* bf2  = (const float*)d_in[17];
    float* out = (float*)d_out;
    (void)in_sizes; (void)n_in; (void)out_size; (void)ws_size;

    size_t off = 0;
    auto carve = [&](size_t bytes) {
        void* p = (char*)d_ws + off;
        off += (bytes + 255) & ~(size_t)255;
        return p;
    };
    const size_t NB4 = (size_t)N_NODES * 4;
    const size_t HK4 = (size_t)NCOPY * N_NODES * 4;

    // --- zero zone (one memset covers all) ---
    char* zstart = (char*)d_ws;
    int*   csK_l = (int*)carve(HK4);
    int*   fcK_l = (int*)carve(HK4);
    int*   csK_r = (int*)carve(HK4);
    int*   fcK_r = (int*)carve(HK4);
    float* pool_l = (float*)carve((size_t)N_GRAPHS * H_DIM * 4);
    float* pool_r = (float*)carve((size_t)N_GRAPHS * H_DIM * 4);
    size_t zbytes = off;

    float* dso_l = (float*)carve(NB4);
    float* dsi_l = (float*)carve(NB4);
    float* dso_r = (float*)carve(NB4);
    float* dsi_r = (float*)carve(NB4);
    int*   cnt_l = (int*)carve(NB4);
    int*   cnt_r = (int*)carve(NB4);
    int*   rp_l  = (int*)carve((size_t)(N_NODES + 1) * 4);
    int*   rp_r  = (int*)carve((size_t)(N_NODES + 1) * 4);
    int*   col_l = (int*)carve((size_t)N_EDGES * 4);
    int*   col_r = (int*)carve((size_t)N_EDGES * 4);
    int*   rk_l  = (int*)carve((size_t)N_EDGES * 4);
    int*   rk_r  = (int*)carve((size_t)N_EDGES * 4);
    int*   bs_l  = (int*)carve((size_t)SCAN_BLOCKS * 4);
    int*   bs_r  = (int*)carve((size_t)SCAN_BLOCKS * 4);

    float*          bufA = (float*)carve((size_t)N_NODES * H_DIM * 4);
    unsigned short* bufH = (unsigned short*)carve((size_t)N_NODES * H_DIM * 2);

    hipMemsetAsync(zstart, 0, zbytes, stream);

    const int EB = 256, EG = (N_EDGES + EB - 1) / EB;
    const int NG = (N_NODES + 255) / 256;
    dim3 ggrid(H_DIM / 128, (N_NODES + 127) / 128);

    // --- CSR for both streams ---
    hist_kernel<<<dim3(EG, 2), EB, 0, stream>>>(src_l, dst_l, csK_l, fcK_l, rk_l,
                                                src_r, dst_r, csK_r, fcK_r, rk_r);
    deg_base_kernel<<<dim3(NG, 2), 256, 0, stream>>>(csK_l, fcK_l, dso_l, dsi_l, cnt_l,
                                                     csK_r, fcK_r, dso_r, dsi_r, cnt_r);
    scan1_kernel<<<dim3(SCAN_BLOCKS, 2), 256, 0, stream>>>(cnt_l, rp_l, bs_l, cnt_r, rp_r, bs_r);
    scan2_kernel<<<dim3(1, 2), 256, 0, stream>>>(bs_l, bs_r, SCAN_BLOCKS);
    scan3_kernel<<<dim3(SCAN_BLOCKS, 2), 256, 0, stream>>>(rp_l, bs_l, rp_r, bs_r);
    scatter_kernel<<<dim3(EG, 2), EB, 0, stream>>>(src_l, dst_l, rp_l, fcK_l, rk_l, col_l,
                                                   src_r, dst_r, rp_r, fcK_r, rk_r, col_r);

    const float* xs[2]   = { xl, xr };
    const float* dsos[2] = { dso_l, dso_r };
    const float* dsis[2] = { dsi_l, dsi_r };
    const int* rps[2]    = { rp_l, rp_r };
    const int* cols[2]   = { col_l, col_r };
    const int* gids[2]   = { gid_l, gid_r };
    float* pools[2]      = { pool_l, pool_r };

    for (int s = 0; s < 2; ++s) {
        agg_f32_kernel<<<N_NODES / 2, 256, 0, stream>>>(xs[s], dsos[s], rps[s], cols[s], bufA);
        gemm_mfma<K0PAD, FIN_DIM><<<ggrid, 256, 0, stream>>>(bufA, W0, b0, dsis[s], bufH, N_NODES);
        agg_bf16_kernel<<<N_NODES / 2, 256, 0, stream>>>(bufH, dsos[s], rps[s], cols[s], bufA);
        gemm_mfma<H_DIM, H_DIM><<<ggrid, 256, 0, stream>>>(bufA, W1, b1, dsis[s], bufH, N_NODES);
        agg_bf16_kernel<<<N_NODES / 2, 256, 0, stream>>>(bufH, dsos[s], rps[s], cols[s], bufA);
        gemm_mfma<H_DIM, H_DIM><<<ggrid, 256, 0, stream>>>(bufA, W2, b2, dsis[s], bufH, N_NODES);

        pool_kernel<<<(N_NODES + 63) / 64, 256, 0, stream>>>(bufH, gids[s], pools[s]);
    }

    mlp_kernel<<<N_GRAPHS, 256, 0, stream>>>(pool_l, pool_r, Wf1, bf1, Wf2, bf2, out);
}

// Round 6
// 973.703 us; speedup vs baseline: 1.5739x; 1.0582x over previous
//
#include <hip/hip_runtime.h>

#define N_NODES 50000
#define N_EDGES 800000
#define N_GRAPHS 100
#define FIN_DIM 74
#define H_DIM 256
#define K0PAD 96
#define NCOPY 8
#define EG 3125            // N_EDGES / 256
#define AGG_BLOCKS 25000   // N_NODES / 2
#define GEMM_BLKS 782      // 2 n-tiles * 391 m-tiles
#define POOL_BLKS 782      // ceil(N_NODES/64)
#define SCAN_BLOCKS 196    // ceil(N_NODES/256)

typedef float f32x4 __attribute__((ext_vector_type(4)));
typedef float f32x2 __attribute__((ext_vector_type(2)));
typedef unsigned short us2 __attribute__((ext_vector_type(2)));
typedef unsigned short us4 __attribute__((ext_vector_type(4)));
typedef unsigned short us8 __attribute__((ext_vector_type(8)));
typedef __bf16 bf16x8 __attribute__((ext_vector_type(8)));

__device__ __forceinline__ unsigned short f2bf(float x) {
    unsigned u = __builtin_bit_cast(unsigned, x);
    u += 0x7fff + ((u >> 16) & 1);
    return (unsigned short)(u >> 16);
}
__device__ __forceinline__ float bf2f(unsigned short h) {
    return __builtin_bit_cast(float, (unsigned)h << 16);
}

// ================= device bodies (all LDS-free except gemm) =================

// histogram: 8-way privatized counts + per-edge rank (copy k = bid & 7)
__device__ __forceinline__ void hist_body(int bid, const int* __restrict__ src,
                                          const int* __restrict__ dst,
                                          int* __restrict__ csK, int* __restrict__ fcK,
                                          int* __restrict__ rk) {
    int e = bid * 256 + threadIdx.x;
    if (e < N_EDGES) {
        int k = bid & (NCOPY - 1);
        rk[e] = atomicAdd(&fcK[k * N_NODES + dst[e]], 1);
        atomicAdd(&csK[k * N_NODES + src[e]], 1);
    }
}

// atomic-free scatter: col[rp[d] + base_k[d] + rk[e]] = src[e]
__device__ __forceinline__ void scat_body(int bid, const int* __restrict__ src,
                                          const int* __restrict__ dst,
                                          const int* __restrict__ rp,
                                          const int* __restrict__ fcK,
                                          const int* __restrict__ rk,
                                          int* __restrict__ col) {
    int e = bid * 256 + threadIdx.x;
    if (e < N_EDGES) {
        int k = bid & (NCOPY - 1);
        int d = dst[e];
        col[rp[d] + fcK[k * N_NODES + d] + rk[e]] = src[e];
    }
}

// layer-0 aggregate: f32 input (74 cols, pad to 96); 2 nodes / 256-thread block
__device__ __forceinline__ void agg_f32_body(int nb, const float* __restrict__ h,
                                             const float* __restrict__ dso,
                                             const int* __restrict__ rp,
                                             const int* __restrict__ col,
                                             float* __restrict__ A) {
    int n = nb * 2 + (threadIdx.x >> 7);
    int f = threadIdx.x & 127;
    int beg = rp[n], end = rp[n + 1];
    if (f < FIN_DIM) {
        float acc0 = 0.f, acc1 = 0.f;
        int j = beg;
        for (; j + 3 < end; j += 4) {
            int s0 = col[j], s1 = col[j + 1], s2 = col[j + 2], s3 = col[j + 3];
            float d0 = dso[s0], d1 = dso[s1], d2 = dso[s2], d3 = dso[s3];
            float h0 = h[(size_t)s0 * FIN_DIM + f];
            float h1 = h[(size_t)s1 * FIN_DIM + f];
            float h2 = h[(size_t)s2 * FIN_DIM + f];
            float h3 = h[(size_t)s3 * FIN_DIM + f];
            acc0 += h0 * d0 + h1 * d1;
            acc1 += h2 * d2 + h3 * d3;
        }
        for (; j < end; ++j) {
            int s = col[j];
            acc0 += h[(size_t)s * FIN_DIM + f] * dso[s];
        }
        A[(size_t)n * K0PAD + f] = acc0 + acc1;
    } else if (f < K0PAD) {
        A[(size_t)n * K0PAD + f] = 0.0f;
    }
}

// hidden aggregate: bf16 input (256 cols); 2 nodes / block, 2 cols / thread
__device__ __forceinline__ void agg_bf16_body(int nb, const unsigned short* __restrict__ h,
                                              const float* __restrict__ dso,
                                              const int* __restrict__ rp,
                                              const int* __restrict__ col,
                                              float* __restrict__ A) {
    int n = nb * 2 + (threadIdx.x >> 7);
    int f2 = (threadIdx.x & 127) * 2;
    int beg = rp[n], end = rp[n + 1];
    float a0 = 0.f, a1 = 0.f, b0 = 0.f, b1 = 0.f;
    int j = beg;
    for (; j + 3 < end; j += 4) {
        int s0 = col[j], s1 = col[j + 1], s2 = col[j + 2], s3 = col[j + 3];
        float d0 = dso[s0], d1 = dso[s1], d2 = dso[s2], d3 = dso[s3];
        us2 v0 = *(const us2*)&h[(size_t)s0 * H_DIM + f2];
        us2 v1 = *(const us2*)&h[(size_t)s1 * H_DIM + f2];
        us2 v2 = *(const us2*)&h[(size_t)s2 * H_DIM + f2];
        us2 v3 = *(const us2*)&h[(size_t)s3 * H_DIM + f2];
        a0 += bf2f(v0[0]) * d0 + bf2f(v1[0]) * d1;
        a1 += bf2f(v0[1]) * d0 + bf2f(v1[1]) * d1;
        b0 += bf2f(v2[0]) * d2 + bf2f(v3[0]) * d3;
        b1 += bf2f(v2[1]) * d2 + bf2f(v3[1]) * d3;
    }
    for (; j < end; ++j) {
        int s = col[j];
        float d = dso[s];
        us2 v = *(const us2*)&h[(size_t)s * H_DIM + f2];
        a0 += bf2f(v[0]) * d;
        a1 += bf2f(v[1]) * d;
    }
    f32x2 r = { a0 + b0, a1 + b1 };
    *(f32x2*)&A[(size_t)n * H_DIM + f2] = r;
}

// sum-pool 64 nodes / block (gid sorted)
__device__ __forceinline__ void pool_body(int nb, const unsigned short* __restrict__ h,
                                          const int* __restrict__ gid,
                                          float* __restrict__ pool) {
    int n0 = nb * 64;
    int f = threadIdx.x;
    int end = min(n0 + 64, N_NODES);
    float acc = 0.0f;
    int gcur = gid[n0];
    for (int i = n0; i < end; ++i) {
        int g = gid[i];
        if (g != gcur) {
            atomicAdd(&pool[(size_t)gcur * H_DIM + f], acc);
            acc = 0.0f;
            gcur = g;
        }
        acc += bf2f(h[(size_t)i * H_DIM + f]);
    }
    atomicAdd(&pool[(size_t)gcur * H_DIM + f], acc);
}

// MFMA GEMM body: C = bf16(relu((A@W)*dsi + bias)); split bf16 hi/lo, 3 passes.
template<int K, int KW>
__device__ __forceinline__ void gemm_body(int id, const float* __restrict__ A,
                                          const float* __restrict__ W,
                                          const float* __restrict__ bias,
                                          const float* __restrict__ dsi,
                                          unsigned short* __restrict__ C,
                                          unsigned short* smem) {
    unsigned short (*Ah)[32] = (unsigned short(*)[32])smem;
    unsigned short (*Al)[32] = Ah + 128;
    unsigned short (*Bh)[36] = (unsigned short(*)[36])(smem + 2 * 128 * 32);
    unsigned short (*Bl)[36] = Bh + 128;
    const int M = N_NODES;

    int tid = threadIdx.x;
    int lane = tid & 63, wid = tid >> 6;
    int wm = (wid >> 1) * 64, wn = (wid & 1) * 64;
    int bm = (id >> 1) * 128, bn = (id & 1) * 128;

    f32x4 acc[4][4] = {};
    int r0 = wm + (lane & 15);
    int c0 = wn + (lane & 15);
    int kA = (lane >> 4) * 8;

    for (int k0 = 0; k0 < K; k0 += 32) {
        #pragma unroll
        for (int i = 0; i < 4; ++i) {
            int q = tid + i * 256;
            int row = q >> 3, k4 = (q & 7) * 4;
            int gm = bm + row;
            f32x4 v = {0.f, 0.f, 0.f, 0.f};
            if (gm < M) v = *(const f32x4*)(A + (size_t)gm * K + k0 + k4);
            us4 h, l;
            #pragma unroll
            for (int j = 0; j < 4; ++j) {
                unsigned short hh = f2bf(v[j]);
                h[j] = hh;
                l[j] = f2bf(v[j] - bf2f(hh));
            }
            *(us4*)&Ah[row][k4] = h;
            *(us4*)&Al[row][k4] = l;
        }
        {
            int colx = tid & 127, kg = tid >> 7;
            us4 h[4], l[4];
            #pragma unroll
            for (int g = 0; g < 4; ++g) {
                #pragma unroll
                for (int j = 0; j < 4; ++j) {
                    int gk = k0 + kg * 16 + g * 4 + j;
                    float w = 0.f;
                    if (gk < KW) w = W[(size_t)gk * H_DIM + bn + colx];
                    unsigned short hh = f2bf(w);
                    h[g][j] = hh;
                    l[g][j] = f2bf(w - bf2f(hh));
                }
            }
            #pragma unroll
            for (int g = 0; g < 4; ++g) {
                *(us4*)&Bh[colx][kg * 16 + g * 4] = h[g];
                *(us4*)&Bl[colx][kg * 16 + g * 4] = l[g];
            }
        }
        __syncthreads();

        bf16x8 ah[4], al[4], bh[4], bl[4];
        #pragma unroll
        for (int m = 0; m < 4; ++m) {
            ah[m] = __builtin_bit_cast(bf16x8, *(const us8*)&Ah[r0 + m * 16][kA]);
            al[m] = __builtin_bit_cast(bf16x8, *(const us8*)&Al[r0 + m * 16][kA]);
        }
        #pragma unroll
        for (int n = 0; n < 4; ++n) {
            us4 x0 = *(const us4*)&Bh[c0 + n * 16][kA];
            us4 x1 = *(const us4*)&Bh[c0 + n * 16][kA + 4];
            us8 x;
            x[0] = x0[0]; x[1] = x0[1]; x[2] = x0[2]; x[3] = x0[3];
            x[4] = x1[0]; x[5] = x1[1]; x[6] = x1[2]; x[7] = x1[3];
            bh[n] = __builtin_bit_cast(bf16x8, x);
            us4 y0 = *(const us4*)&Bl[c0 + n * 16][kA];
            us4 y1 = *(const us4*)&Bl[c0 + n * 16][kA + 4];
            us8 y;
            y[0] = y0[0]; y[1] = y0[1]; y[2] = y0[2]; y[3] = y0[3];
            y[4] = y1[0]; y[5] = y1[1]; y[6] = y1[2]; y[7] = y1[3];
            bl[n] = __builtin_bit_cast(bf16x8, y);
        }

        #pragma unroll
        for (int m = 0; m < 4; ++m)
            #pragma unroll
            for (int n = 0; n < 4; ++n) {
                acc[m][n] = __builtin_amdgcn_mfma_f32_16x16x32_bf16(al[m], bh[n], acc[m][n], 0, 0, 0);
                acc[m][n] = __builtin_amdgcn_mfma_f32_16x16x32_bf16(ah[m], bl[n], acc[m][n], 0, 0, 0);
                acc[m][n] = __builtin_amdgcn_mfma_f32_16x16x32_bf16(ah[m], bh[n], acc[m][n], 0, 0, 0);
            }
        __syncthreads();
    }

    int rowq = (lane >> 4) * 4;
    #pragma unroll
    for (int n = 0; n < 4; ++n) {
        int gn = bn + wn + n * 16 + (lane & 15);
        float bv = bias[gn];
        #pragma unroll
        for (int m = 0; m < 4; ++m) {
            #pragma unroll
            for (int j = 0; j < 4; ++j) {
                int gm = bm + wm + m * 16 + rowq + j;
                if (gm < M) {
                    C[(size_t)gm * H_DIM + gn] = f2bf(fmaxf(acc[m][n][j] * dsi[gm] + bv, 0.0f));
                }
            }
        }
    }
}

// ================= kernels =================

__global__ void hist_kernel(const int* __restrict__ src, const int* __restrict__ dst,
                            int* __restrict__ csK, int* __restrict__ fcK, int* __restrict__ rk) {
    hist_body(blockIdx.x, src, dst, csK, fcK, rk);
}

__device__ __forceinline__ int block_excl_scan(int v, int* wsums) {
    int lane = threadIdx.x & 63, w = threadIdx.x >> 6;
    int x = v;
    #pragma unroll
    for (int ofs = 1; ofs < 64; ofs <<= 1) {
        int y = __shfl_up(x, ofs, 64);
        if (lane >= ofs) x += y;
    }
    if (lane == 63) wsums[w] = x;
    __syncthreads();
    int wo = 0;
    #pragma unroll
    for (int k = 0; k < 4; ++k) if (k < w) wo += wsums[k];
    return wo + x - v;
}

// degrees + copy-bases + per-block scan pass (merged)
__global__ void deg_scan1_kernel(int* __restrict__ csK, int* __restrict__ fcK,
                                 float* __restrict__ dso, float* __restrict__ dsi,
                                 int* __restrict__ rp, int* __restrict__ bs) {
    __shared__ int ws[4];
    int i = blockIdx.x * 256 + threadIdx.x;
    int v = 0;
    if (i < N_NODES) {
        int cs = 0;
        #pragma unroll
        for (int k = 0; k < NCOPY; ++k) cs += csK[k * N_NODES + i];
        dso[i] = rsqrtf(fmaxf((float)cs, 1.0f));
        int b = 0;
        #pragma unroll
        for (int k = 0; k < NCOPY; ++k) {
            int t = fcK[k * N_NODES + i];
            fcK[k * N_NODES + i] = b;
            b += t;
        }
        dsi[i] = rsqrtf(fmaxf((float)b, 1.0f));
        v = b;
    }
    int ex = block_excl_scan(v, ws);
    if (i < N_NODES) rp[i] = ex;
    if (threadIdx.x == 255) bs[blockIdx.x] = ex + v;
}

__global__ void scan2_kernel(int* __restrict__ bs, int nb) {
    __shared__ int ws[4];
    int i = threadIdx.x;
    int v = (i < nb) ? bs[i] : 0;
    int ex = block_excl_scan(v, ws);
    __syncthreads();
    if (i < nb) bs[i] = ex;
}

__global__ void scan3_kernel(int* __restrict__ rp, const int* __restrict__ bs) {
    int i = blockIdx.x * 256 + threadIdx.x;
    if (i < N_NODES) rp[i] += bs[blockIdx.x];
    if (i == 0) rp[N_NODES] = N_EDGES;
}

__global__ void scat_kernel(const int* __restrict__ src, const int* __restrict__ dst,
                            const int* __restrict__ rp, const int* __restrict__ fcK,
                            const int* __restrict__ rk, int* __restrict__ col) {
    scat_body(blockIdx.x, src, dst, rp, fcK, rk, col);
}

// fused: histR (blocks [0,EG)) || aggL0 f32 (blocks [EG, EG+AGG_BLOCKS))
__global__ void fuse_hist_agg0(const int* __restrict__ srcB, const int* __restrict__ dstB,
                               int* __restrict__ csKB, int* __restrict__ fcKB, int* __restrict__ rkB,
                               const float* __restrict__ xA, const float* __restrict__ dsoA,
                               const int* __restrict__ rpA, const int* __restrict__ colA,
                               float* __restrict__ outA) {
    int bid = blockIdx.x;
    if (bid < EG) hist_body(bid, srcB, dstB, csKB, fcKB, rkB);
    else          agg_f32_body(bid - EG, xA, dsoA, rpA, colA, outA);
}

// fused: scatR (blocks [0,EG)) || aggL bf16
__global__ void fuse_scat_agg(const int* __restrict__ srcB, const int* __restrict__ dstB,
                              const int* __restrict__ rpB, const int* __restrict__ fcKB,
                              const int* __restrict__ rkB, int* __restrict__ colB,
                              const unsigned short* __restrict__ hA, const float* __restrict__ dsoA,
                              const int* __restrict__ rpA, const int* __restrict__ colA,
                              float* __restrict__ outA) {
    int bid = blockIdx.x;
    if (bid < EG) scat_body(bid, srcB, dstB, rpB, fcKB, rkB, colB);
    else          agg_bf16_body(bid - EG, hA, dsoA, rpA, colA, outA);
}

// fused: aggL2 bf16 (even) || aggR0 f32 (odd) — parity interleave for co-residency
__global__ void fuse_agg_agg(const unsigned short* __restrict__ hA, const float* __restrict__ dsoA,
                             const int* __restrict__ rpA, const int* __restrict__ colA,
                             float* __restrict__ outA,
                             const float* __restrict__ xB, const float* __restrict__ dsoB,
                             const int* __restrict__ rpB, const int* __restrict__ colB,
                             float* __restrict__ outB) {
    int bid = blockIdx.x;
    int nb = bid >> 1;
    if (bid & 1) agg_f32_body(nb, xB, dsoB, rpB, colB, outB);
    else         agg_bf16_body(nb, hA, dsoA, rpA, colA, outA);
}

// fused: poolL (blocks [0,POOL_BLKS)) || aggR bf16
__global__ void fuse_pool_agg(const unsigned short* __restrict__ hP, const int* __restrict__ gidP,
                              float* __restrict__ poolP,
                              const unsigned short* __restrict__ hA, const float* __restrict__ dsoA,
                              const int* __restrict__ rpA, const int* __restrict__ colA,
                              float* __restrict__ outA) {
    int bid = blockIdx.x;
    if (bid < POOL_BLKS) pool_body(bid, hP, gidP, poolP);
    else                 agg_bf16_body(bid - POOL_BLKS, hA, dsoA, rpA, colA, outA);
}

template<int K, int KW>
__global__ __launch_bounds__(256, 2) void gemm_kernel(
        const float* __restrict__ A, const float* __restrict__ W,
        const float* __restrict__ bias, const float* __restrict__ dsi,
        unsigned short* __restrict__ C) {
    __shared__ unsigned short smem[2 * 128 * 32 + 2 * 128 * 36];
    gemm_body<K, KW>(blockIdx.x, A, W, bias, dsi, C, smem);
}

// two GEMMs batched in one dispatch (same LDS/occupancy profile; kills tail-wave)
__global__ __launch_bounds__(256, 2) void gemm_pair_kernel(
        const float* __restrict__ A1, const float* __restrict__ W1_, const float* __restrict__ b1_,
        const float* __restrict__ dsi1, unsigned short* __restrict__ C1,
        const float* __restrict__ A2, const float* __restrict__ W2_, const float* __restrict__ b2_,
        const float* __restrict__ dsi2, unsigned short* __restrict__ C2) {
    __shared__ unsigned short smem[2 * 128 * 32 + 2 * 128 * 36];
    int bid = blockIdx.x;
    if (bid < GEMM_BLKS) gemm_body<H_DIM, H_DIM>(bid, A1, W1_, b1_, dsi1, C1, smem);
    else                 gemm_body<K0PAD, FIN_DIM>(bid - GEMM_BLKS, A2, W2_, b2_, dsi2, C2, smem);
}

__global__ void pool_kernel(const unsigned short* __restrict__ h, const int* __restrict__ gid,
                            float* __restrict__ pool) {
    pool_body(blockIdx.x, h, gid, pool);
}

__global__ void agg_bf16_kernel(const unsigned short* __restrict__ h, const float* __restrict__ dso,
                                const int* __restrict__ rp, const int* __restrict__ col,
                                float* __restrict__ A) {
    agg_bf16_body(blockIdx.x, h, dso, rp, col, A);
}

__global__ __launch_bounds__(256) void mlp_kernel(
        const float* __restrict__ pl, const float* __restrict__ pr,
        const float* __restrict__ Wf1, const float* __restrict__ bf1,
        const float* __restrict__ Wf2, const float* __restrict__ bf2,
        float* __restrict__ out) {
    __shared__ float z[512];
    __shared__ float red[256];
    int g = blockIdx.x, tid = threadIdx.x;
    z[tid] = pl[(size_t)g * H_DIM + tid];
    z[tid + 256] = pr[(size_t)g * H_DIM + tid];
    __syncthreads();
    float t = bf1[tid];
    #pragma unroll 8
    for (int k = 0; k < 512; ++k) t += z[k] * Wf1[(size_t)k * H_DIM + tid];
    t = fmaxf(t, 0.0f);
    red[tid] = t * Wf2[tid];
    __syncthreads();
    for (int ofs = 128; ofs > 0; ofs >>= 1) {
        if (tid < ofs) red[tid] += red[tid + ofs];
        __syncthreads();
    }
    if (tid == 0) out[g] = red[0] + bf2[0];
}

// ================= driver =================

extern "C" void kernel_launch(void* const* d_in, const int* in_sizes, int n_in,
                              void* d_out, int out_size, void* d_ws, size_t ws_size,
                              hipStream_t stream) {
    const float* xl   = (const float*)d_in[0];
    const float* xr   = (const float*)d_in[1];
    const int* src_l  = (const int*)d_in[2];
    const int* dst_l  = (const int*)d_in[3];
    const int* src_r  = (const int*)d_in[4];
    const int* dst_r  = (const int*)d_in[5];
    const int* gid_l  = (const int*)d_in[6];
    const int* gid_r  = (const int*)d_in[7];
    const float* W0   = (const float*)d_in[8];
    const float* b0   = (const float*)d_in[9];
    const float* W1   = (const float*)d_in[10];
    const float* b1   = (const float*)d_in[11];
    const float* W2   = (const float*)d_in[12];
    const float* b2   = (const float*)d_in[13];
    const float* Wf1  = (const float*)d_in[14];
    const float* bf1  = (const float*)d_in[15];
    const float* Wf2  = (const float*)d_in[16];
    const float* bf2  = (const float*)d_in[17];
    float* out = (float*)d_out;
    (void)in_sizes; (void)n_in; (void)out_size; (void)ws_size;

    size_t off = 0;
    auto carve = [&](size_t bytes) {
        void* p = (char*)d_ws + off;
        off += (bytes + 255) & ~(size_t)255;
        return p;
    };
    const size_t NB4 = (size_t)N_NODES * 4;
    const size_t HK4 = (size_t)NCOPY * N_NODES * 4;

    // --- zero zone (one memset) ---
    char* zstart = (char*)d_ws;
    int*   csK_l = (int*)carve(HK4);
    int*   fcK_l = (int*)carve(HK4);
    int*   csK_r = (int*)carve(HK4);
    int*   fcK_r = (int*)carve(HK4);
    float* pool_l = (float*)carve((size_t)N_GRAPHS * H_DIM * 4);
    float* pool_r = (float*)carve((size_t)N_GRAPHS * H_DIM * 4);
    size_t zbytes = off;

    float* dso_l = (float*)carve(NB4);
    float* dsi_l = (float*)carve(NB4);
    float* dso_r = (float*)carve(NB4);
    float* dsi_r = (float*)carve(NB4);
    int*   rp_l  = (int*)carve((size_t)(N_NODES + 1) * 4);
    int*   rp_r  = (int*)carve((size_t)(N_NODES + 1) * 4);
    int*   col_l = (int*)carve((size_t)N_EDGES * 4);
    int*   col_r = (int*)carve((size_t)N_EDGES * 4);
    int*   rk_l  = (int*)carve((size_t)N_EDGES * 4);
    int*   rk_r  = (int*)carve((size_t)N_EDGES * 4);
    int*   bs_l  = (int*)carve((size_t)SCAN_BLOCKS * 4);
    int*   bs_r  = (int*)carve((size_t)SCAN_BLOCKS * 4);

    float*          bufA_l = (float*)carve((size_t)N_NODES * H_DIM * 4);
    unsigned short* bufH_l = (unsigned short*)carve((size_t)N_NODES * H_DIM * 2);
    float*          bufA_r = (float*)carve((size_t)N_NODES * H_DIM * 4);
    unsigned short* bufH_r = (unsigned short*)carve((size_t)N_NODES * H_DIM * 2);

    hipMemsetAsync(zstart, 0, zbytes, stream);

    // ---- stream L CSR ----
    hist_kernel<<<EG, 256, 0, stream>>>(src_l, dst_l, csK_l, fcK_l, rk_l);
    deg_scan1_kernel<<<SCAN_BLOCKS, 256, 0, stream>>>(csK_l, fcK_l, dso_l, dsi_l, rp_l, bs_l);
    scan2_kernel<<<1, 256, 0, stream>>>(bs_l, SCAN_BLOCKS);
    scan3_kernel<<<SCAN_BLOCKS, 256, 0, stream>>>(rp_l, bs_l);
    scat_kernel<<<EG, 256, 0, stream>>>(src_l, dst_l, rp_l, fcK_l, rk_l, col_l);

    // ---- pipelined main: L compute with R CSR/aggs riding along ----
    // aggL0 || histR
    fuse_hist_agg0<<<EG + AGG_BLOCKS, 256, 0, stream>>>(
        src_r, dst_r, csK_r, fcK_r, rk_r,
        xl, dso_l, rp_l, col_l, bufA_l);
    gemm_kernel<K0PAD, FIN_DIM><<<GEMM_BLKS, 256, 0, stream>>>(bufA_l, W0, b0, dsi_l, bufH_l);

    deg_scan1_kernel<<<SCAN_BLOCKS, 256, 0, stream>>>(csK_r, fcK_r, dso_r, dsi_r, rp_r, bs_r);
    scan2_kernel<<<1, 256, 0, stream>>>(bs_r, SCAN_BLOCKS);
    scan3_kernel<<<SCAN_BLOCKS, 256, 0, stream>>>(rp_r, bs_r);

    // aggL1 || scatR
    fuse_scat_agg<<<EG + AGG_BLOCKS, 256, 0, stream>>>(
        src_r, dst_r, rp_r, fcK_r, rk_r, col_r,
        bufH_l, dso_l, rp_l, col_l, bufA_l);
    gemm_kernel<H_DIM, H_DIM><<<GEMM_BLKS, 256, 0, stream>>>(bufA_l, W1, b1, dsi_l, bufH_l);

    // aggL2 || aggR0
    fuse_agg_agg<<<2 * AGG_BLOCKS, 256, 0, stream>>>(
        bufH_l, dso_l, rp_l, col_l, bufA_l,
        xr, dso_r, rp_r, col_r, bufA_r);

    // gemmL2 + gemmR0 batched
    gemm_pair_kernel<<<2 * GEMM_BLKS, 256, 0, stream>>>(
        bufA_l, W2, b2, dsi_l, bufH_l,
        bufA_r, W0, b0, dsi_r, bufH_r);

    // poolL || aggR1
    fuse_pool_agg<<<POOL_BLKS + AGG_BLOCKS, 256, 0, stream>>>(
        bufH_l, gid_l, pool_l,
        bufH_r, dso_r, rp_r, col_r, bufA_r);
    gemm_kernel<H_DIM, H_DIM><<<GEMM_BLKS, 256, 0, stream>>>(bufA_r, W1, b1, dsi_r, bufH_r);

    // R tail
    agg_bf16_kernel<<<AGG_BLOCKS, 256, 0, stream>>>(bufH_r, dso_r, rp_r, col_r, bufA_r);
    gemm_kernel<H_DIM, H_DIM><<<GEMM_BLKS, 256, 0, stream>>>(bufA_r, W2, b2, dsi_r, bufH_r);
    pool_kernel<<<POOL_BLKS, 256, 0, stream>>>(bufH_r, gid_r, pool_r);

    mlp_kernel<<<N_GRAPHS, 256, 0, stream>>>(pool_l, pool_r, Wf1, bf1, Wf2, bf2, out);
}

// Round 7
// 921.275 us; speedup vs baseline: 1.6635x; 1.0569x over previous
//
#include <hip/hip_runtime.h>

#define N_NODES 50000
#define N_EDGES 800000
#define N_GRAPHS 100
#define FIN_DIM 74
#define X_LD 80            // padded bf16 x' row stride
#define K0PAD 96
#define H_DIM 256
#define EG 3125            // N_EDGES / 256
#define XSCALE_BLKS 15625  // N_NODES * X_LD / 256 (exact)
#define AGG_BLOCKS 25000   // N_NODES / 2
#define GEMM_BLKS 782      // 2 n-tiles * 391 m-tiles
#define POOL_BLKS 782
#define SCAN_BLOCKS 196

typedef float f32x4 __attribute__((ext_vector_type(4)));
typedef unsigned short us2 __attribute__((ext_vector_type(2)));
typedef unsigned short us4 __attribute__((ext_vector_type(4)));
typedef unsigned short us8 __attribute__((ext_vector_type(8)));
typedef __bf16 bf16x8 __attribute__((ext_vector_type(8)));

__device__ __forceinline__ unsigned short f2bf(float x) {
    unsigned u = __builtin_bit_cast(unsigned, x);
    u += 0x7fff + ((u >> 16) & 1);
    return (unsigned short)(u >> 16);
}
__device__ __forceinline__ float bf2f(unsigned short h) {
    return __builtin_bit_cast(float, (unsigned)h << 16);
}

// ================= device bodies =================

// 1 atomic pair per edge; rank = global rank within dst (single copy)
__device__ __forceinline__ void hist_body(int bid, const int* __restrict__ src,
                                          const int* __restrict__ dst,
                                          int* __restrict__ cs, int* __restrict__ fc,
                                          int* __restrict__ rk) {
    int e = bid * 256 + threadIdx.x;
    if (e < N_EDGES) {
        rk[e] = atomicAdd(&fc[dst[e]], 1);
        atomicAdd(&cs[src[e]], 1);
    }
}

// atomic-free scatter
__device__ __forceinline__ void scat_body(int bid, const int* __restrict__ src,
                                          const int* __restrict__ dst,
                                          const int* __restrict__ rp,
                                          const int* __restrict__ rk,
                                          int* __restrict__ col) {
    int e = bid * 256 + threadIdx.x;
    if (e < N_EDGES) {
        int d = dst[e];
        col[rp[d] + rk[e]] = src[e];
    }
}

// x' = bf16(x * dso), padded [N][80]
__device__ __forceinline__ void xscale_body(int bid, const float* __restrict__ x,
                                            const float* __restrict__ dso,
                                            unsigned short* __restrict__ xp) {
    int id = bid * 256 + threadIdx.x;
    int n = id / X_LD, f = id - n * X_LD;
    float v = (f < FIN_DIM) ? x[(size_t)n * FIN_DIM + f] * dso[n] : 0.f;
    xp[id] = f2bf(v);
}

// aggregate: A[n][f] = bf16( sum_{s in in(n)} h[s][f] ); h is pre-scaled by dso.
// 2 nodes / 256-thread block; thread owns 2 cols (us2).
template<int LDI, int LDO>
__device__ __forceinline__ void agg_body(int nb, const unsigned short* __restrict__ h,
                                         const int* __restrict__ rp,
                                         const int* __restrict__ col,
                                         unsigned short* __restrict__ A) {
    int n = nb * 2 + (threadIdx.x >> 7);
    int f2 = (threadIdx.x & 127) * 2;
    if (f2 >= LDI) {
        if (f2 < LDO) { us2 z = {0, 0}; *(us2*)&A[(size_t)n * LDO + f2] = z; }
        return;
    }
    int beg = rp[n], end = rp[n + 1];
    float a0 = 0.f, a1 = 0.f, b0 = 0.f, b1 = 0.f;
    int j = beg;
    for (; j + 3 < end; j += 4) {
        int s0 = col[j], s1 = col[j + 1], s2 = col[j + 2], s3 = col[j + 3];
        us2 v0 = *(const us2*)&h[(size_t)s0 * LDI + f2];
        us2 v1 = *(const us2*)&h[(size_t)s1 * LDI + f2];
        us2 v2 = *(const us2*)&h[(size_t)s2 * LDI + f2];
        us2 v3 = *(const us2*)&h[(size_t)s3 * LDI + f2];
        a0 += bf2f(v0[0]) + bf2f(v1[0]);
        a1 += bf2f(v0[1]) + bf2f(v1[1]);
        b0 += bf2f(v2[0]) + bf2f(v3[0]);
        b1 += bf2f(v2[1]) + bf2f(v3[1]);
    }
    for (; j < end; ++j) {
        int s = col[j];
        us2 v = *(const us2*)&h[(size_t)s * LDI + f2];
        a0 += bf2f(v[0]);
        a1 += bf2f(v[1]);
    }
    us2 r = { f2bf(a0 + b0), f2bf(a1 + b1) };
    *(us2*)&A[(size_t)n * LDO + f2] = r;
}

// sum-pool 64 nodes / block (gid sorted), raw bf16 h
__device__ __forceinline__ void pool_body(int nb, const unsigned short* __restrict__ h,
                                          const int* __restrict__ gid,
                                          float* __restrict__ pool) {
    int n0 = nb * 64;
    int f = threadIdx.x;
    int end = min(n0 + 64, N_NODES);
    float acc = 0.0f;
    int gcur = gid[n0];
    for (int i = n0; i < end; ++i) {
        int g = gid[i];
        if (g != gcur) {
            atomicAdd(&pool[(size_t)gcur * H_DIM + f], acc);
            acc = 0.0f;
            gcur = g;
        }
        acc += bf2f(h[(size_t)i * H_DIM + f]);
    }
    atomicAdd(&pool[(size_t)gcur * H_DIM + f], acc);
}

// 1-pass bf16 MFMA GEMM: C = bf16( relu((A@W)*dsi + bias) * (scale?scale:1) )
// A: [M][K] bf16, W: [KW][256] f32 (rows >= KW treated as 0), C: [M][256] bf16.
template<int K, int KW>
__device__ __forceinline__ void gemm_body(int id, const unsigned short* __restrict__ A,
                                          const float* __restrict__ W,
                                          const float* __restrict__ bias,
                                          const float* __restrict__ dsi,
                                          const float* __restrict__ scale,
                                          unsigned short* __restrict__ C,
                                          unsigned short* smem) {
    unsigned short (*Ah)[40] = (unsigned short(*)[40])smem;            // 128x32, pad->40
    unsigned short (*Bh)[36] = (unsigned short(*)[36])(smem + 128 * 40);
    const int M = N_NODES;

    int tid = threadIdx.x;
    int lane = tid & 63, wid = tid >> 6;
    int wm = (wid >> 1) * 64, wn = (wid & 1) * 64;
    int bm = (id >> 1) * 128, bn = (id & 1) * 128;

    f32x4 acc[4][4] = {};
    int r0 = wm + (lane & 15);
    int c0 = wn + (lane & 15);
    int kA = (lane >> 4) * 8;

    for (int k0 = 0; k0 < K; k0 += 32) {
        // stage A (128x32 bf16): 512 us8 loads, 2 iters
        #pragma unroll
        for (int i = 0; i < 2; ++i) {
            int q = tid + i * 256;
            int row = q >> 2, k8 = (q & 3) * 8;
            int gm = bm + row;
            us8 v = {0, 0, 0, 0, 0, 0, 0, 0};
            if (gm < M) v = *(const us8*)(A + (size_t)gm * K + k0 + k8);
            *(us8*)&Ah[row][k8] = v;
        }
        // stage B (32x128 f32 -> bf16 transposed [col][k])
        {
            int colx = tid & 127, kg = tid >> 7;
            #pragma unroll
            for (int g = 0; g < 4; ++g) {
                us4 hh;
                #pragma unroll
                for (int j = 0; j < 4; ++j) {
                    int gk = k0 + kg * 16 + g * 4 + j;
                    float w = (gk < KW) ? W[(size_t)gk * H_DIM + bn + colx] : 0.f;
                    hh[j] = f2bf(w);
                }
                *(us4*)&Bh[colx][kg * 16 + g * 4] = hh;
            }
        }
        __syncthreads();

        bf16x8 ah[4], bh[4];
        #pragma unroll
        for (int m = 0; m < 4; ++m)
            ah[m] = __builtin_bit_cast(bf16x8, *(const us8*)&Ah[r0 + m * 16][kA]);
        #pragma unroll
        for (int n = 0; n < 4; ++n) {
            us4 x0 = *(const us4*)&Bh[c0 + n * 16][kA];
            us4 x1 = *(const us4*)&Bh[c0 + n * 16][kA + 4];
            us8 x;
            x[0] = x0[0]; x[1] = x0[1]; x[2] = x0[2]; x[3] = x0[3];
            x[4] = x1[0]; x[5] = x1[1]; x[6] = x1[2]; x[7] = x1[3];
            bh[n] = __builtin_bit_cast(bf16x8, x);
        }

        #pragma unroll
        for (int m = 0; m < 4; ++m)
            #pragma unroll
            for (int n = 0; n < 4; ++n)
                acc[m][n] = __builtin_amdgcn_mfma_f32_16x16x32_bf16(ah[m], bh[n], acc[m][n], 0, 0, 0);
        __syncthreads();
    }

    int rowq = (lane >> 4) * 4;
    #pragma unroll
    for (int n = 0; n < 4; ++n) {
        int gn = bn + wn + n * 16 + (lane & 15);
        float bv = bias[gn];
        #pragma unroll
        for (int m = 0; m < 4; ++m) {
            #pragma unroll
            for (int j = 0; j < 4; ++j) {
                int gm = bm + wm + m * 16 + rowq + j;
                if (gm < M) {
                    float r = fmaxf(acc[m][n][j] * dsi[gm] + bv, 0.0f);
                    if (scale) r *= scale[gm];
                    C[(size_t)gm * H_DIM + gn] = f2bf(r);
                }
            }
        }
    }
}

// ================= kernels =================

__device__ __forceinline__ int block_excl_scan(int v, int* wsums) {
    int lane = threadIdx.x & 63, w = threadIdx.x >> 6;
    int x = v;
    #pragma unroll
    for (int ofs = 1; ofs < 64; ofs <<= 1) {
        int y = __shfl_up(x, ofs, 64);
        if (lane >= ofs) x += y;
    }
    if (lane == 63) wsums[w] = x;
    __syncthreads();
    int wo = 0;
    #pragma unroll
    for (int k = 0; k < 4; ++k) if (k < w) wo += wsums[k];
    return wo + x - v;
}

__global__ void hist_kernel(const int* __restrict__ src, const int* __restrict__ dst,
                            int* __restrict__ cs, int* __restrict__ fc, int* __restrict__ rk) {
    hist_body(blockIdx.x, src, dst, cs, fc, rk);
}

__global__ void deg_scan1_kernel(const int* __restrict__ cs, const int* __restrict__ fc,
                                 float* __restrict__ dso, float* __restrict__ dsi,
                                 int* __restrict__ rp, int* __restrict__ bs) {
    __shared__ int ws[4];
    int i = blockIdx.x * 256 + threadIdx.x;
    int v = 0;
    if (i < N_NODES) {
        dso[i] = rsqrtf(fmaxf((float)cs[i], 1.0f));
        v = fc[i];
        dsi[i] = rsqrtf(fmaxf((float)v, 1.0f));
    }
    int ex = block_excl_scan(v, ws);
    if (i < N_NODES) rp[i] = ex;
    if (threadIdx.x == 255) bs[blockIdx.x] = ex + v;
}

__global__ void scan2_kernel(int* __restrict__ bs, int nb) {
    __shared__ int ws[4];
    int i = threadIdx.x;
    int v = (i < nb) ? bs[i] : 0;
    int ex = block_excl_scan(v, ws);
    __syncthreads();
    if (i < nb) bs[i] = ex;
}

__global__ void scan3_kernel(int* __restrict__ rp, const int* __restrict__ bs) {
    int i = blockIdx.x * 256 + threadIdx.x;
    if (i < N_NODES) rp[i] += bs[blockIdx.x];
    if (i == 0) rp[N_NODES] = N_EDGES;
}

// histR || scatL || xscaleL
__global__ void fuse_hsx(const int* __restrict__ srcR, const int* __restrict__ dstR,
                         int* __restrict__ csR, int* __restrict__ fcR, int* __restrict__ rkR,
                         const int* __restrict__ srcL, const int* __restrict__ dstL,
                         const int* __restrict__ rpL, const int* __restrict__ rkL,
                         int* __restrict__ colL,
                         const float* __restrict__ xL, const float* __restrict__ dsoL,
                         unsigned short* __restrict__ xpL) {
    int bid = blockIdx.x;
    if (bid < EG)            hist_body(bid, srcR, dstR, csR, fcR, rkR);
    else if (bid < 2 * EG)   scat_body(bid - EG, srcL, dstL, rpL, rkL, colL);
    else                     xscale_body(bid - 2 * EG, xL, dsoL, xpL);
}

// deg_scanR || aggL0
__global__ void fuse_dsagg0(const int* __restrict__ csR, const int* __restrict__ fcR,
                            float* __restrict__ dsoR, float* __restrict__ dsiR,
                            int* __restrict__ rpR, int* __restrict__ bsR,
                            const unsigned short* __restrict__ xpL, const int* __restrict__ rpL,
                            const int* __restrict__ colL, unsigned short* __restrict__ AL) {
    __shared__ int ws[4];
    int bid = blockIdx.x;
    if (bid < SCAN_BLOCKS) {
        int i = bid * 256 + threadIdx.x;
        int v = 0;
        if (i < N_NODES) {
            dsoR[i] = rsqrtf(fmaxf((float)csR[i], 1.0f));
            v = fcR[i];
            dsiR[i] = rsqrtf(fmaxf((float)v, 1.0f));
        }
        int ex = block_excl_scan(v, ws);
        if (i < N_NODES) rpR[i] = ex;
        if (threadIdx.x == 255) bsR[bid] = ex + v;
    } else {
        agg_body<X_LD, K0PAD>(bid - SCAN_BLOCKS, xpL, rpL, colL, AL);
    }
}

// scatR || xscaleR || aggL1
__global__ void fuse_sxagg(const int* __restrict__ srcR, const int* __restrict__ dstR,
                           const int* __restrict__ rpR, const int* __restrict__ rkR,
                           int* __restrict__ colR,
                           const float* __restrict__ xR, const float* __restrict__ dsoR,
                           unsigned short* __restrict__ xpR,
                           const unsigned short* __restrict__ hL, const int* __restrict__ rpL,
                           const int* __restrict__ colL, unsigned short* __restrict__ AL) {
    int bid = blockIdx.x;
    if (bid < EG)                      scat_body(bid, srcR, dstR, rpR, rkR, colR);
    else if (bid < EG + XSCALE_BLKS)   xscale_body(bid - EG, xR, dsoR, xpR);
    else                               agg_body<H_DIM, H_DIM>(bid - EG - XSCALE_BLKS, hL, rpL, colL, AL);
}

// aggL2 (even) || aggR0 (odd)
__global__ void fuse_agg_agg(const unsigned short* __restrict__ hL, const int* __restrict__ rpL,
                             const int* __restrict__ colL, unsigned short* __restrict__ AL,
                             const unsigned short* __restrict__ xpR, const int* __restrict__ rpR,
                             const int* __restrict__ colR, unsigned short* __restrict__ AR) {
    int bid = blockIdx.x;
    if (bid & 1) agg_body<X_LD, K0PAD>(bid >> 1, xpR, rpR, colR, AR);
    else         agg_body<H_DIM, H_DIM>(bid >> 1, hL, rpL, colL, AL);
}

// poolL || aggR1
__global__ void fuse_pool_agg(const unsigned short* __restrict__ hP, const int* __restrict__ gidP,
                              float* __restrict__ poolP,
                              const unsigned short* __restrict__ hA, const int* __restrict__ rpA,
                              const int* __restrict__ colA, unsigned short* __restrict__ outA) {
    int bid = blockIdx.x;
    if (bid < POOL_BLKS) pool_body(bid, hP, gidP, poolP);
    else                 agg_body<H_DIM, H_DIM>(bid - POOL_BLKS, hA, rpA, colA, outA);
}

template<int K, int KW>
__global__ __launch_bounds__(256) void gemm_kernel(
        const unsigned short* __restrict__ A, const float* __restrict__ W,
        const float* __restrict__ bias, const float* __restrict__ dsi,
        const float* __restrict__ scale, unsigned short* __restrict__ C) {
    __shared__ unsigned short smem[128 * 40 + 128 * 36];
    gemm_body<K, KW>(blockIdx.x, A, W, bias, dsi, scale, C, smem);
}

// gemmL2 (K=256, raw) + gemmR0 (K=96, *dso_r) in one dispatch
__global__ __launch_bounds__(256) void gemm_pair_kernel(
        const unsigned short* __restrict__ A1, const float* __restrict__ Wa,
        const float* __restrict__ ba, const float* __restrict__ dsi1, unsigned short* __restrict__ C1,
        const unsigned short* __restrict__ A2, const float* __restrict__ Wb,
        const float* __restrict__ bb, const float* __restrict__ dsi2,
        const float* __restrict__ sc2, unsigned short* __restrict__ C2) {
    __shared__ unsigned short smem[128 * 40 + 128 * 36];
    int bid = blockIdx.x;
    if (bid < GEMM_BLKS) gemm_body<H_DIM, H_DIM>(bid, A1, Wa, ba, dsi1, nullptr, C1, smem);
    else                 gemm_body<K0PAD, FIN_DIM>(bid - GEMM_BLKS, A2, Wb, bb, dsi2, sc2, C2, smem);
}

__global__ void agg_kernel(const unsigned short* __restrict__ h, const int* __restrict__ rp,
                           const int* __restrict__ col, unsigned short* __restrict__ A) {
    agg_body<H_DIM, H_DIM>(blockIdx.x, h, rp, col, A);
}

__global__ void pool_kernel(const unsigned short* __restrict__ h, const int* __restrict__ gid,
                            float* __restrict__ pool) {
    pool_body(blockIdx.x, h, gid, pool);
}

__global__ __launch_bounds__(256) void mlp_kernel(
        const float* __restrict__ pl, const float* __restrict__ pr,
        const float* __restrict__ Wf1, const float* __restrict__ bf1,
        const float* __restrict__ Wf2, const float* __restrict__ bf2,
        float* __restrict__ out) {
    __shared__ float z[512];
    __shared__ float red[256];
    int g = blockIdx.x, tid = threadIdx.x;
    z[tid] = pl[(size_t)g * H_DIM + tid];
    z[tid + 256] = pr[(size_t)g * H_DIM + tid];
    __syncthreads();
    float t = bf1[tid];
    #pragma unroll 8
    for (int k = 0; k < 512; ++k) t += z[k] * Wf1[(size_t)k * H_DIM + tid];
    t = fmaxf(t, 0.0f);
    red[tid] = t * Wf2[tid];
    __syncthreads();
    for (int ofs = 128; ofs > 0; ofs >>= 1) {
        if (tid < ofs) red[tid] += red[tid + ofs];
        __syncthreads();
    }
    if (tid == 0) out[g] = red[0] + bf2[0];
}

// ================= driver =================

extern "C" void kernel_launch(void* const* d_in, const int* in_sizes, int n_in,
                              void* d_out, int out_size, void* d_ws, size_t ws_size,
                              hipStream_t stream) {
    const float* xl   = (const float*)d_in[0];
    const float* xr   = (const float*)d_in[1];
    const int* src_l  = (const int*)d_in[2];
    const int* dst_l  = (const int*)d_in[3];
    const int* src_r  = (const int*)d_in[4];
    const int* dst_r  = (const int*)d_in[5];
    const int* gid_l  = (const int*)d_in[6];
    const int* gid_r  = (const int*)d_in[7];
    const float* W0   = (const float*)d_in[8];
    const float* b0   = (const float*)d_in[9];
    const float* W1   = (const float*)d_in[10];
    const float* b1   = (const float*)d_in[11];
    const float* W2   = (const float*)d_in[12];
    const float* b2   = (const float*)d_in[13];
    const float* Wf1  = (const float*)d_in[14];
    const float* bf1  = (const float*)d_in[15];
    const float* Wf2  = (const float*)d_in[16];
    const float* bf2  = (const float*)d_in[17];
    float* out = (float*)d_out;
    (void)in_sizes; (void)n_in; (void)out_size; (void)ws_size;

    size_t off = 0;
    auto carve = [&](size_t bytes) {
        void* p = (char*)d_ws + off;
        off += (bytes + 255) & ~(size_t)255;
        return p;
    };
    const size_t NB4 = (size_t)N_NODES * 4;

    // zero zone (single memset)
    char* zstart = (char*)d_ws;
    int*   cs_l   = (int*)carve(NB4);
    int*   fc_l   = (int*)carve(NB4);
    int*   cs_r   = (int*)carve(NB4);
    int*   fc_r   = (int*)carve(NB4);
    float* pool_l = (float*)carve((size_t)N_GRAPHS * H_DIM * 4);
    float* pool_r = (float*)carve((size_t)N_GRAPHS * H_DIM * 4);
    size_t zbytes = off;

    float* dso_l = (float*)carve(NB4);
    float* dsi_l = (float*)carve(NB4);
    float* dso_r = (float*)carve(NB4);
    float* dsi_r = (float*)carve(NB4);
    int*   rp_l  = (int*)carve((size_t)(N_NODES + 1) * 4);
    int*   rp_r  = (int*)carve((size_t)(N_NODES + 1) * 4);
    int*   col_l = (int*)carve((size_t)N_EDGES * 4);
    int*   col_r = (int*)carve((size_t)N_EDGES * 4);
    int*   rk_l  = (int*)carve((size_t)N_EDGES * 4);
    int*   rk_r  = (int*)carve((size_t)N_EDGES * 4);
    int*   bs_l  = (int*)carve((size_t)SCAN_BLOCKS * 4);
    int*   bs_r  = (int*)carve((size_t)SCAN_BLOCKS * 4);

    unsigned short* xp_l  = (unsigned short*)carve((size_t)N_NODES * X_LD * 2);
    unsigned short* xp_r  = (unsigned short*)carve((size_t)N_NODES * X_LD * 2);
    unsigned short* bufA_l = (unsigned short*)carve((size_t)N_NODES * H_DIM * 2);
    unsigned short* bufA_r = (unsigned short*)carve((size_t)N_NODES * H_DIM * 2);
    unsigned short* bufH_l = (unsigned short*)carve((size_t)N_NODES * H_DIM * 2);
    unsigned short* bufH_r = (unsigned short*)carve((size_t)N_NODES * H_DIM * 2);

    hipMemsetAsync(zstart, 0, zbytes, stream);

    // ---- stream L CSR ----
    hist_kernel<<<EG, 256, 0, stream>>>(src_l, dst_l, cs_l, fc_l, rk_l);
    deg_scan1_kernel<<<SCAN_BLOCKS, 256, 0, stream>>>(cs_l, fc_l, dso_l, dsi_l, rp_l, bs_l);
    scan2_kernel<<<1, 256, 0, stream>>>(bs_l, SCAN_BLOCKS);
    scan3_kernel<<<SCAN_BLOCKS, 256, 0, stream>>>(rp_l, bs_l);

    // histR || scatL || xscaleL
    fuse_hsx<<<2 * EG + XSCALE_BLKS, 256, 0, stream>>>(
        src_r, dst_r, cs_r, fc_r, rk_r,
        src_l, dst_l, rp_l, rk_l, col_l,
        xl, dso_l, xp_l);

    // deg_scanR || aggL0
    fuse_dsagg0<<<SCAN_BLOCKS + AGG_BLOCKS, 256, 0, stream>>>(
        cs_r, fc_r, dso_r, dsi_r, rp_r, bs_r,
        xp_l, rp_l, col_l, bufA_l);
    scan2_kernel<<<1, 256, 0, stream>>>(bs_r, SCAN_BLOCKS);
    scan3_kernel<<<SCAN_BLOCKS, 256, 0, stream>>>(rp_r, bs_r);

    // gemmL0 (writes h0 * dso_l)
    gemm_kernel<K0PAD, FIN_DIM><<<GEMM_BLKS, 256, 0, stream>>>(bufA_l, W0, b0, dsi_l, dso_l, bufH_l);

    // scatR || xscaleR || aggL1
    fuse_sxagg<<<EG + XSCALE_BLKS + AGG_BLOCKS, 256, 0, stream>>>(
        src_r, dst_r, rp_r, rk_r, col_r,
        xr, dso_r, xp_r,
        bufH_l, rp_l, col_l, bufA_l);

    // gemmL1 (writes h1 * dso_l)
    gemm_kernel<H_DIM, H_DIM><<<GEMM_BLKS, 256, 0, stream>>>(bufA_l, W1, b1, dsi_l, dso_l, bufH_l);

    // aggL2 || aggR0
    fuse_agg_agg<<<2 * AGG_BLOCKS, 256, 0, stream>>>(
        bufH_l, rp_l, col_l, bufA_l,
        xp_r, rp_r, col_r, bufA_r);

    // gemmL2 (raw) + gemmR0 (*dso_r)
    gemm_pair_kernel<<<2 * GEMM_BLKS, 256, 0, stream>>>(
        bufA_l, W2, b2, dsi_l, bufH_l,
        bufA_r, W0, b0, dsi_r, dso_r, bufH_r);

    // poolL || aggR1
    fuse_pool_agg<<<POOL_BLKS + AGG_BLOCKS, 256, 0, stream>>>(
        bufH_l, gid_l, pool_l,
        bufH_r, rp_r, col_r, bufA_r);

    // gemmR1 (*dso_r)
    gemm_kernel<H_DIM, H_DIM><<<GEMM_BLKS, 256, 0, stream>>>(bufA_r, W1, b1, dsi_r, dso_r, bufH_r);

    // R tail
    agg_kernel<<<AGG_BLOCKS, 256, 0, stream>>>(bufH_r, rp_r, col_r, bufA_r);
    gemm_kernel<H_DIM, H_DIM><<<GEMM_BLKS, 256, 0, stream>>>(bufA_r, W2, b2, dsi_r, nullptr, bufH_r);
    pool_kernel<<<POOL_BLKS, 256, 0, stream>>>(bufH_r, gid_r, pool_r);

    mlp_kernel<<<N_GRAPHS, 256, 0, stream>>>(pool_l, pool_r, Wf1, bf1, Wf2, bf2, out);
}

// Round 9
// 757.192 us; speedup vs baseline: 2.0240x; 1.2167x over previous
//
#include <hip/hip_runtime.h>

#define N_NODES 50000
#define N_EDGES 800000
#define N_GRAPHS 100
#define FIN_DIM 74
#define K0 96              // layer-0 K (padded), 6 slices of 16
#define H_DIM 256          // hidden width, 8 slices of 32
#define EG 3125            // N_EDGES / 256
#define XS_BLKS 18750      // N_NODES*96/256
#define WCONV_BLKS 608     // (256*96 + 2*256*256)/256
#define AGG0_BLKS 3128     // ceil(N/128)=391 node-groups * 8 slices
#define AGGH_BLKS 6256     // ceil(N/64)=782 * 8
#define GEMM_BLKS 782      // 391 m-tiles * 2 n-tiles
#define POOL_BLKS 782
#define SCAN_BLOCKS 196

typedef float f32x4 __attribute__((ext_vector_type(4)));
typedef unsigned int u32x4 __attribute__((ext_vector_type(4)));
typedef unsigned short us8 __attribute__((ext_vector_type(8)));
typedef __bf16 bf16x8 __attribute__((ext_vector_type(8)));

__device__ __forceinline__ unsigned short f2bf(float x) {
    unsigned u = __builtin_bit_cast(unsigned, x);
    u += 0x7fff + ((u >> 16) & 1);
    return (unsigned short)(u >> 16);
}
__device__ __forceinline__ float bf2f(unsigned short h) {
    return __builtin_bit_cast(float, (unsigned)h << 16);
}
// accumulate 8 bf16 (as us8) into 8 f32 via shift/mask unpack
__device__ __forceinline__ void acc8(float* a, us8 v) {
    u32x4 w = __builtin_bit_cast(u32x4, v);
    #pragma unroll
    for (int i = 0; i < 4; ++i) {
        a[2 * i]     += __builtin_bit_cast(float, w[i] << 16);
        a[2 * i + 1] += __builtin_bit_cast(float, w[i] & 0xffff0000u);
    }
}

// ================= device bodies =================

__device__ __forceinline__ void hist_body(int bid, const int* __restrict__ src,
                                          const int* __restrict__ dst,
                                          int* __restrict__ cs, int* __restrict__ fc,
                                          int* __restrict__ rk) {
    int e = bid * 256 + threadIdx.x;
    if (e < N_EDGES) {
        rk[e] = atomicAdd(&fc[dst[e]], 1);
        atomicAdd(&cs[src[e]], 1);
    }
}

__device__ __forceinline__ void scat_body(int bid, const int* __restrict__ src,
                                          const int* __restrict__ dst,
                                          const int* __restrict__ rp,
                                          const int* __restrict__ rk,
                                          int* __restrict__ col) {
    int e = bid * 256 + threadIdx.x;
    if (e < N_EDGES) {
        int d = dst[e];
        col[rp[d] + rk[e]] = src[e];
    }
}

// x' = bf16(x*dso), slice-major [6][N][16], zeros for f>=74
__device__ __forceinline__ void xscale_body(int bid, const float* __restrict__ x,
                                            const float* __restrict__ dso,
                                            unsigned short* __restrict__ xp) {
    int id = bid * 256 + threadIdx.x;            // over N*96
    int n = id / 96, f = id - n * 96;
    float v = (f < FIN_DIM) ? x[(size_t)n * FIN_DIM + f] * dso[n] : 0.f;
    xp[(size_t)(f >> 4) * (N_NODES * 16) + (size_t)n * 16 + (f & 15)] = f2bf(v);
}

// W -> transposed bf16 Wt[col][k] (3 matrices back-to-back)
__device__ __forceinline__ void wconv_body(int bid, const float* __restrict__ W0,
                                           const float* __restrict__ W1,
                                           const float* __restrict__ W2,
                                           unsigned short* __restrict__ Wt) {
    int id = bid * 256 + threadIdx.x;
    if (id < 256 * 96) {
        int n = id / 96, k = id - n * 96;
        float v = (k < FIN_DIM) ? W0[(size_t)k * H_DIM + n] : 0.f;
        Wt[id] = f2bf(v);
    } else if (id < 256 * 96 + 65536) {
        int id2 = id - 256 * 96;
        int n = id2 >> 8, k = id2 & 255;
        Wt[id] = f2bf(W1[(size_t)k * H_DIM + n]);
    } else {
        int id3 = id - 256 * 96 - 65536;
        int n = id3 >> 8, k = id3 & 255;
        Wt[id] = f2bf(W2[(size_t)k * H_DIM + n]);
    }
}

// XCD-sliced aggregate. SW cols/slice, NACT slices with real data, NSL total slices.
// Block handles (abid>>3)'th node group on slice cg; thread = (node, 8-col chunk).
template<int SW, int NACT, int NSL>
__device__ __forceinline__ void agg_body(int abid, int cg,
                                         const unsigned short* __restrict__ h,
                                         const int* __restrict__ rp,
                                         const int* __restrict__ col,
                                         unsigned short* __restrict__ A) {
    const int CPB = SW / 8;        // chunks per node (threads per node)
    const int NPB = 256 / CPB;     // nodes per block
    if (cg >= NSL) return;
    int slot = threadIdx.x & (CPB - 1);
    int n = (abid >> 3) * NPB + threadIdx.x / CPB;
    if (n >= N_NODES) return;
    unsigned short* dst = A + (size_t)cg * (N_NODES * SW) + (size_t)n * SW + slot * 8;
    if (cg >= NACT) { us8 z = {}; *(us8*)dst = z; return; }
    const unsigned short* hs = h + (size_t)cg * (N_NODES * SW) + slot * 8;
    int beg = rp[n], end = rp[n + 1];
    float a[8] = {};
    int j = beg;
    for (; j + 3 < end; j += 4) {
        int s0 = col[j], s1 = col[j + 1], s2 = col[j + 2], s3 = col[j + 3];
        us8 v0 = *(const us8*)(hs + (size_t)s0 * SW);
        us8 v1 = *(const us8*)(hs + (size_t)s1 * SW);
        us8 v2 = *(const us8*)(hs + (size_t)s2 * SW);
        us8 v3 = *(const us8*)(hs + (size_t)s3 * SW);
        acc8(a, v0); acc8(a, v1); acc8(a, v2); acc8(a, v3);
    }
    for (; j < end; ++j)
        acc8(a, *(const us8*)(hs + (size_t)col[j] * SW));
    us8 r;
    #pragma unroll
    for (int i = 0; i < 8; ++i) r[i] = f2bf(a[i]);
    *(us8*)dst = r;
}

// sum-pool 64 nodes/block; h slice-major [8][N][32]
__device__ __forceinline__ void pool_body(int nb, const unsigned short* __restrict__ h,
                                          const int* __restrict__ gid,
                                          float* __restrict__ pool) {
    int n0 = nb * 64;
    int f = threadIdx.x;
    const unsigned short* hf = h + (size_t)(f >> 5) * (N_NODES * 32) + (f & 31);
    int end = min(n0 + 64, N_NODES);
    float acc = 0.0f;
    int gcur = gid[n0];
    for (int i = n0; i < end; ++i) {
        int g = gid[i];
        if (g != gcur) {
            atomicAdd(&pool[(size_t)gcur * H_DIM + f], acc);
            acc = 0.0f;
            gcur = g;
        }
        acc += bf2f(hf[(size_t)i * 32]);
    }
    atomicAdd(&pool[(size_t)gcur * H_DIM + f], acc);
}

// MFMA GEMM: C(slice-major [8][N][32]) = bf16(relu((A@Wt^T)*dsi + bias) * (scale?:1))
// A slice-major [K/SW][N][SW] bf16; Wt[col][k] bf16.
template<int K, int SW>
__device__ __forceinline__ void gemm_body(int id, const unsigned short* __restrict__ A,
                                          const unsigned short* __restrict__ Wt,
                                          const float* __restrict__ bias,
                                          const float* __restrict__ dsi,
                                          const float* __restrict__ scale,
                                          unsigned short* __restrict__ C,
                                          unsigned short* smem) {
    unsigned short (*Ah)[40] = (unsigned short(*)[40])smem;
    unsigned short (*Bh)[40] = (unsigned short(*)[40])(smem + 128 * 40);
    const int M = N_NODES;

    int tid = threadIdx.x;
    int lane = tid & 63, wid = tid >> 6;
    int wm = (wid >> 1) * 64, wn = (wid & 1) * 64;
    int bm = (id >> 1) * 128, bn = (id & 1) * 128;

    f32x4 acc[4][4] = {};
    int r0 = wm + (lane & 15);
    int c0 = wn + (lane & 15);
    int kA = (lane >> 4) * 8;

    for (int k0 = 0; k0 < K; k0 += 32) {
        // stage A: 128 rows x 32 k (slice-major source)
        #pragma unroll
        for (int i = 0; i < 2; ++i) {
            int q = tid + i * 256;
            int row = q >> 2, k8 = (q & 3) * 8;
            int gm = bm + row;
            int kk = k0 + k8;
            us8 v = {};
            if (gm < M)
                v = *(const us8*)(A + (size_t)(kk / SW) * ((size_t)N_NODES * SW)
                                    + (size_t)gm * SW + (kk % SW));
            *(us8*)&Ah[row][k8] = v;
        }
        // stage B: Wt[bn+col][k0..k0+32) — each thread loads 16 k (two us8)
        {
            int colx = tid & 127, kg = tid >> 7;
            const unsigned short* wsrc = Wt + (size_t)(bn + colx) * K + k0 + kg * 16;
            us8 w0 = *(const us8*)(wsrc);
            us8 w1 = *(const us8*)(wsrc + 8);
            *(us8*)&Bh[colx][kg * 16] = w0;
            *(us8*)&Bh[colx][kg * 16 + 8] = w1;
        }
        __syncthreads();

        bf16x8 ah[4], bh[4];
        #pragma unroll
        for (int m = 0; m < 4; ++m)
            ah[m] = __builtin_bit_cast(bf16x8, *(const us8*)&Ah[r0 + m * 16][kA]);
        #pragma unroll
        for (int n = 0; n < 4; ++n)
            bh[n] = __builtin_bit_cast(bf16x8, *(const us8*)&Bh[c0 + n * 16][kA]);

        #pragma unroll
        for (int m = 0; m < 4; ++m)
            #pragma unroll
            for (int n = 0; n < 4; ++n)
                acc[m][n] = __builtin_amdgcn_mfma_f32_16x16x32_bf16(ah[m], bh[n], acc[m][n], 0, 0, 0);
        __syncthreads();
    }

    int rowq = (lane >> 4) * 4;
    #pragma unroll
    for (int n = 0; n < 4; ++n) {
        int gn = bn + wn + n * 16 + (lane & 15);
        float bv = bias[gn];
        unsigned short* cs = C + (size_t)(gn >> 5) * (N_NODES * 32) + (gn & 31);
        #pragma unroll
        for (int m = 0; m < 4; ++m) {
            #pragma unroll
            for (int j = 0; j < 4; ++j) {
                int gm = bm + wm + m * 16 + rowq + j;
                if (gm < M) {
                    float r = fmaxf(acc[m][n][j] * dsi[gm] + bv, 0.0f);
                    if (scale) r *= scale[gm];
                    cs[(size_t)gm * 32] = f2bf(r);
                }
            }
        }
    }
}

// ================= kernels =================

__device__ __forceinline__ int block_excl_scan(int v, int* wsums) {
    int lane = threadIdx.x & 63, w = threadIdx.x >> 6;
    int x = v;
    #pragma unroll
    for (int ofs = 1; ofs < 64; ofs <<= 1) {
        int y = __shfl_up(x, ofs, 64);
        if (lane >= ofs) x += y;
    }
    if (lane == 63) wsums[w] = x;
    __syncthreads();
    int wo = 0;
    #pragma unroll
    for (int k = 0; k < 4; ++k) if (k < w) wo += wsums[k];
    return wo + x - v;
}

// wconv || histL
__global__ void k_whist(const float* __restrict__ W0, const float* __restrict__ W1,
                        const float* __restrict__ W2, unsigned short* __restrict__ Wt,
                        const int* __restrict__ src, const int* __restrict__ dst,
                        int* __restrict__ cs, int* __restrict__ fc, int* __restrict__ rk) {
    int bid = blockIdx.x;
    if (bid < WCONV_BLKS) wconv_body(bid, W0, W1, W2, Wt);
    else                  hist_body(bid - WCONV_BLKS, src, dst, cs, fc, rk);
}

__global__ void deg_scan1_kernel(const int* __restrict__ cs, const int* __restrict__ fc,
                                 float* __restrict__ dso, float* __restrict__ dsi,
                                 int* __restrict__ rp, int* __restrict__ bs) {
    __shared__ int ws[4];
    int i = blockIdx.x * 256 + threadIdx.x;
    int v = 0;
    if (i < N_NODES) {
        dso[i] = rsqrtf(fmaxf((float)cs[i], 1.0f));
        v = fc[i];
        dsi[i] = rsqrtf(fmaxf((float)v, 1.0f));
    }
    int ex = block_excl_scan(v, ws);
    if (i < N_NODES) rp[i] = ex;
    if (threadIdx.x == 255) bs[blockIdx.x] = ex + v;
}

__global__ void scan2_kernel(int* __restrict__ bs, int nb) {
    __shared__ int ws[4];
    int i = threadIdx.x;
    int v = (i < nb) ? bs[i] : 0;
    int ex = block_excl_scan(v, ws);
    __syncthreads();
    if (i < nb) bs[i] = ex;
}

__global__ void scan3_kernel(int* __restrict__ rp, const int* __restrict__ bs) {
    int i = blockIdx.x * 256 + threadIdx.x;
    if (i < N_NODES) rp[i] += bs[blockIdx.x];
    if (i == 0) rp[N_NODES] = N_EDGES;
}

// histR || scatL || xscaleL
__global__ void fuse_hsx(const int* __restrict__ srcR, const int* __restrict__ dstR,
                         int* __restrict__ csR, int* __restrict__ fcR, int* __restrict__ rkR,
                         const int* __restrict__ srcL, const int* __restrict__ dstL,
                         const int* __restrict__ rpL, const int* __restrict__ rkL,
                         int* __restrict__ colL,
                         const float* __restrict__ xL, const float* __restrict__ dsoL,
                         unsigned short* __restrict__ xpL) {
    int bid = blockIdx.x;
    if (bid < EG)            hist_body(bid, srcR, dstR, csR, fcR, rkR);
    else if (bid < 2 * EG)   scat_body(bid - EG, srcL, dstL, rpL, rkL, colL);
    else                     xscale_body(bid - 2 * EG, xL, dsoL, xpL);
}

// deg_scanR || aggL0
__global__ void fuse_dsagg0(const int* __restrict__ csR, const int* __restrict__ fcR,
                            float* __restrict__ dsoR, float* __restrict__ dsiR,
                            int* __restrict__ rpR, int* __restrict__ bsR,
                            const unsigned short* __restrict__ xpL, const int* __restrict__ rpL,
                            const int* __restrict__ colL, unsigned short* __restrict__ AL) {
    __shared__ int ws[4];
    int bid = blockIdx.x;
    if (bid < SCAN_BLOCKS) {
        int i = bid * 256 + threadIdx.x;
        int v = 0;
        if (i < N_NODES) {
            dsoR[i] = rsqrtf(fmaxf((float)csR[i], 1.0f));
            v = fcR[i];
            dsiR[i] = rsqrtf(fmaxf((float)v, 1.0f));
        }
        int ex = block_excl_scan(v, ws);
        if (i < N_NODES) rpR[i] = ex;
        if (threadIdx.x == 255) bsR[bid] = ex + v;
    } else {
        agg_body<16, 5, 6>(bid - SCAN_BLOCKS, blockIdx.x & 7, xpL, rpL, colL, AL);
    }
}

// scatR || xscaleR || aggL1
__global__ void fuse_sxagg(const int* __restrict__ srcR, const int* __restrict__ dstR,
                           const int* __restrict__ rpR, const int* __restrict__ rkR,
                           int* __restrict__ colR,
                           const float* __restrict__ xR, const float* __restrict__ dsoR,
                           unsigned short* __restrict__ xpR,
                           const unsigned short* __restrict__ hL, const int* __restrict__ rpL,
                           const int* __restrict__ colL, unsigned short* __restrict__ AL) {
    int bid = blockIdx.x;
    if (bid < EG)                    scat_body(bid, srcR, dstR, rpR, rkR, colR);
    else if (bid < EG + XS_BLKS)     xscale_body(bid - EG, xR, dsoR, xpR);
    else agg_body<32, 8, 8>(bid - EG - XS_BLKS, blockIdx.x & 7, hL, rpL, colL, AL);
}

// aggL2 || aggR0
__global__ void fuse_agg_agg(const unsigned short* __restrict__ hL, const int* __restrict__ rpL,
                             const int* __restrict__ colL, unsigned short* __restrict__ AL,
                             const unsigned short* __restrict__ xpR, const int* __restrict__ rpR,
                             const int* __restrict__ colR, unsigned short* __restrict__ AR) {
    int bid = blockIdx.x;
    if (bid < AGGH_BLKS) agg_body<32, 8, 8>(bid, blockIdx.x & 7, hL, rpL, colL, AL);
    else agg_body<16, 5, 6>(bid - AGGH_BLKS, blockIdx.x & 7, xpR, rpR, colR, AR);
}

// poolL || aggR1
__global__ void fuse_pool_agg(const unsigned short* __restrict__ hP, const int* __restrict__ gidP,
                              float* __restrict__ poolP,
                              const unsigned short* __restrict__ hA, const int* __restrict__ rpA,
                              const int* __restrict__ colA, unsigned short* __restrict__ outA) {
    int bid = blockIdx.x;
    if (bid < POOL_BLKS) pool_body(bid, hP, gidP, poolP);
    else agg_body<32, 8, 8>(bid - POOL_BLKS, blockIdx.x & 7, hA, rpA, colA, outA);
}

template<int K, int SW>
__global__ __launch_bounds__(256) void gemm_kernel(
        const unsigned short* __restrict__ A, const unsigned short* __restrict__ Wt,
        const float* __restrict__ bias, const float* __restrict__ dsi,
        const float* __restrict__ scale, unsigned short* __restrict__ C) {
    __shared__ unsigned short smem[2 * 128 * 40];
    gemm_body<K, SW>(blockIdx.x, A, Wt, bias, dsi, scale, C, smem);
}

// gemmL2 (K=256, raw) + gemmR0 (K=96, *dso_r)
__global__ __launch_bounds__(256) void gemm_pair_kernel(
        const unsigned short* __restrict__ A1, const unsigned short* __restrict__ Wt2,
        const float* __restrict__ b2_, const float* __restrict__ dsi1, unsigned short* __restrict__ C1,
        const unsigned short* __restrict__ A2, const unsigned short* __restrict__ Wt0,
        const float* __restrict__ b0_, const float* __restrict__ dsi2,
        const float* __restrict__ sc2, unsigned short* __restrict__ C2) {
    __shared__ unsigned short smem[2 * 128 * 40];
    int bid = blockIdx.x;
    if (bid < GEMM_BLKS) gemm_body<H_DIM, 32>(bid, A1, Wt2, b2_, dsi1, nullptr, C1, smem);
    else                 gemm_body<K0, 16>(bid - GEMM_BLKS, A2, Wt0, b0_, dsi2, sc2, C2, smem);
}

__global__ void agg_kernel(const unsigned short* __restrict__ h, const int* __restrict__ rp,
                           const int* __restrict__ col, unsigned short* __restrict__ A) {
    agg_body<32, 8, 8>(blockIdx.x, blockIdx.x & 7, h, rp, col, A);
}

__global__ void pool_kernel(const unsigned short* __restrict__ h, const int* __restrict__ gid,
                            float* __restrict__ pool) {
    pool_body(blockIdx.x, h, gid, pool);
}

__global__ __launch_bounds__(256) void mlp_kernel(
        const float* __restrict__ pl, const float* __restrict__ pr,
        const float* __restrict__ Wf1, const float* __restrict__ bf1,
        const float* __restrict__ Wf2, const float* __restrict__ bf2,
        float* __restrict__ out) {
    __shared__ float z[512];
    __shared__ float red[256];
    int g = blockIdx.x, tid = threadIdx.x;
    z[tid] = pl[(size_t)g * H_DIM + tid];
    z[tid + 256] = pr[(size_t)g * H_DIM + tid];
    __syncthreads();
    float t = bf1[tid];
    #pragma unroll 8
    for (int k = 0; k < 512; ++k) t += z[k] * Wf1[(size_t)k * H_DIM + tid];
    t = fmaxf(t, 0.0f);
    red[tid] = t * Wf2[tid];
    __syncthreads();
    for (int ofs = 128; ofs > 0; ofs >>= 1) {
        if (tid < ofs) red[tid] += red[tid + ofs];
        __syncthreads();
    }
    if (tid == 0) out[g] = red[0] + bf2[0];
}

// ================= driver =================

extern "C" void kernel_launch(void* const* d_in, const int* in_sizes, int n_in,
                              void* d_out, int out_size, void* d_ws, size_t ws_size,
                              hipStream_t stream) {
    const float* xl   = (const float*)d_in[0];
    const float* xr   = (const float*)d_in[1];
    const int* src_l  = (const int*)d_in[2];
    const int* dst_l  = (const int*)d_in[3];
    const int* src_r  = (const int*)d_in[4];
    const int* dst_r  = (const int*)d_in[5];
    const int* gid_l  = (const int*)d_in[6];
    const int* gid_r  = (const int*)d_in[7];
    const float* W0   = (const float*)d_in[8];
    const float* b0   = (const float*)d_in[9];
    const float* W1   = (const float*)d_in[10];
    const float* b1   = (const float*)d_in[11];
    const float* W2   = (const float*)d_in[12];
    const float* b2   = (const float*)d_in[13];
    const float* Wf1  = (const float*)d_in[14];
    const float* bf1  = (const float*)d_in[15];
    const float* Wf2  = (const float*)d_in[16];
    const float* bf2  = (const float*)d_in[17];
    float* out = (float*)d_out;
    (void)in_sizes; (void)n_in; (void)out_size; (void)ws_size;

    size_t off = 0;
    auto carve = [&](size_t bytes) {
        void* p = (char*)d_ws + off;
        off += (bytes + 255) & ~(size_t)255;
        return p;
    };
    const size_t NB4 = (size_t)N_NODES * 4;

    // zero zone (single memset)
    char* zstart = (char*)d_ws;
    int*   cs_l   = (int*)carve(NB4);
    int*   fc_l   = (int*)carve(NB4);
    int*   cs_r   = (int*)carve(NB4);
    int*   fc_r   = (int*)carve(NB4);
    float* pool_l = (float*)carve((size_t)N_GRAPHS * H_DIM * 4);
    float* pool_r = (float*)carve((size_t)N_GRAPHS * H_DIM * 4);
    size_t zbytes = off;

    float* dso_l = (float*)carve(NB4);
    float* dsi_l = (float*)carve(NB4);
    float* dso_r = (float*)carve(NB4);
    float* dsi_r = (float*)carve(NB4);
    int*   rp_l  = (int*)carve((size_t)(N_NODES + 1) * 4);
    int*   rp_r  = (int*)carve((size_t)(N_NODES + 1) * 4);
    int*   col_l = (int*)carve((size_t)N_EDGES * 4);
    int*   col_r = (int*)carve((size_t)N_EDGES * 4);
    int*   rk_l  = (int*)carve((size_t)N_EDGES * 4);
    int*   rk_r  = (int*)carve((size_t)N_EDGES * 4);
    int*   bs_l  = (int*)carve((size_t)SCAN_BLOCKS * 4);
    int*   bs_r  = (int*)carve((size_t)SCAN_BLOCKS * 4);

    unsigned short* Wt    = (unsigned short*)carve((size_t)(256 * 96 + 2 * 65536) * 2);
    unsigned short* Wt0   = Wt;
    unsigned short* Wt1   = Wt + 256 * 96;
    unsigned short* Wt2   = Wt + 256 * 96 + 65536;
    unsigned short* xp_l  = (unsigned short*)carve((size_t)N_NODES * 96 * 2);
    unsigned short* xp_r  = (unsigned short*)carve((size_t)N_NODES * 96 * 2);
    unsigned short* bufA_l = (unsigned short*)carve((size_t)N_NODES * H_DIM * 2);
    unsigned short* bufA_r = (unsigned short*)carve((size_t)N_NODES * H_DIM * 2);
    unsigned short* bufH_l = (unsigned short*)carve((size_t)N_NODES * H_DIM * 2);
    unsigned short* bufH_r = (unsigned short*)carve((size_t)N_NODES * H_DIM * 2);

    hipMemsetAsync(zstart, 0, zbytes, stream);

    // wconv || histL
    k_whist<<<WCONV_BLKS + EG, 256, 0, stream>>>(W0, W1, W2, Wt,
                                                 src_l, dst_l, cs_l, fc_l, rk_l);
    deg_scan1_kernel<<<SCAN_BLOCKS, 256, 0, stream>>>(cs_l, fc_l, dso_l, dsi_l, rp_l, bs_l);
    scan2_kernel<<<1, 256, 0, stream>>>(bs_l, SCAN_BLOCKS);
    scan3_kernel<<<SCAN_BLOCKS, 256, 0, stream>>>(rp_l, bs_l);

    // histR || scatL || xscaleL
    fuse_hsx<<<2 * EG + XS_BLKS, 256, 0, stream>>>(
        src_r, dst_r, cs_r, fc_r, rk_r,
        src_l, dst_l, rp_l, rk_l, col_l,
        xl, dso_l, xp_l);

    // deg_scanR || aggL0
    fuse_dsagg0<<<SCAN_BLOCKS + AGG0_BLKS, 256, 0, stream>>>(
        cs_r, fc_r, dso_r, dsi_r, rp_r, bs_r,
        xp_l, rp_l, col_l, bufA_l);
    scan2_kernel<<<1, 256, 0, stream>>>(bs_r, SCAN_BLOCKS);
    scan3_kernel<<<SCAN_BLOCKS, 256, 0, stream>>>(rp_r, bs_r);

    // gemmL0 (writes h0 * dso_l, slice-major)
    gemm_kernel<K0, 16><<<GEMM_BLKS, 256, 0, stream>>>(bufA_l, Wt0, b0, dsi_l, dso_l, bufH_l);

    // scatR || xscaleR || aggL1
    fuse_sxagg<<<EG + XS_BLKS + AGGH_BLKS, 256, 0, stream>>>(
        src_r, dst_r, rp_r, rk_r, col_r,
        xr, dso_r, xp_r,
        bufH_l, rp_l, col_l, bufA_l);

    // gemmL1 (*dso_l)
    gemm_kernel<H_DIM, 32><<<GEMM_BLKS, 256, 0, stream>>>(bufA_l, Wt1, b1, dsi_l, dso_l, bufH_l);

    // aggL2 || aggR0
    fuse_agg_agg<<<AGGH_BLKS + AGG0_BLKS, 256, 0, stream>>>(
        bufH_l, rp_l, col_l, bufA_l,
        xp_r, rp_r, col_r, bufA_r);

    // gemmL2 (raw) + gemmR0 (*dso_r)
    gemm_pair_kernel<<<2 * GEMM_BLKS, 256, 0, stream>>>(
        bufA_l, Wt2, b2, dsi_l, bufH_l,
        bufA_r, Wt0, b0, dsi_r, dso_r, bufH_r);

    // poolL || aggR1
    fuse_pool_agg<<<POOL_BLKS + AGGH_BLKS, 256, 0, stream>>>(
        bufH_l, gid_l, pool_l,
        bufH_r, rp_r, col_r, bufA_r);

    // gemmR1 (*dso_r)
    gemm_kernel<H_DIM, 32><<<GEMM_BLKS, 256, 0, stream>>>(bufA_r, Wt1, b1, dsi_r, dso_r, bufH_r);

    // R tail
    agg_kernel<<<AGGH_BLKS, 256, 0, stream>>>(bufH_r, rp_r, col_r, bufA_r);
    gemm_kernel<H_DIM, 32><<<GEMM_BLKS, 256, 0, stream>>>(bufA_r, Wt2, b2, dsi_r, nullptr, bufH_r);
    pool_kernel<<<POOL_BLKS, 256, 0, stream>>>(bufH_r, gid_r, pool_r);

    mlp_kernel<<<N_GRAPHS, 256, 0, stream>>>(pool_l, pool_r, Wf1, bf1, Wf2, bf2, out);
}

// Round 10
// 747.637 us; speedup vs baseline: 2.0498x; 1.0128x over previous
//
#include <hip/hip_runtime.h>

#define N_NODES 50000
#define N_EDGES 800000
#define N_GRAPHS 100
#define FIN_DIM 74
#define K0 96              // layer-0 K (padded), 6 slices of 16
#define H_DIM 256          // hidden width, 8 slices of 32
#define EG 3125            // N_EDGES / 256
#define XS_BLKS 18750      // N_NODES*96/256
#define WCONV_BLKS 608     // (256*96 + 2*256*256)/256
#define AGG0_BLKS 3128     // 391 node-groups * 8 slices
#define AGGH_BLKS 6256     // 782 * 8
#define GEMM_BLKS 782      // 391 m-tiles * 2 n-tiles
#define POOL_BLKS 782
#define SCAN_BLOCKS 196

typedef float f32x4 __attribute__((ext_vector_type(4)));
typedef unsigned int u32x4 __attribute__((ext_vector_type(4)));
typedef unsigned short us8 __attribute__((ext_vector_type(8)));
typedef __bf16 bf16x8 __attribute__((ext_vector_type(8)));

__device__ __forceinline__ unsigned short f2bf(float x) {
    unsigned u = __builtin_bit_cast(unsigned, x);
    u += 0x7fff + ((u >> 16) & 1);
    return (unsigned short)(u >> 16);
}
__device__ __forceinline__ float bf2f(unsigned short h) {
    return __builtin_bit_cast(float, (unsigned)h << 16);
}
__device__ __forceinline__ void acc8(float* a, us8 v) {
    u32x4 w = __builtin_bit_cast(u32x4, v);
    #pragma unroll
    for (int i = 0; i < 4; ++i) {
        a[2 * i]     += __builtin_bit_cast(float, w[i] << 16);
        a[2 * i + 1] += __builtin_bit_cast(float, w[i] & 0xffff0000u);
    }
}

// ================= device bodies (R9-proven) =================

__device__ __forceinline__ void hist_body(int bid, const int* __restrict__ src,
                                          const int* __restrict__ dst,
                                          int* __restrict__ cs, int* __restrict__ fc,
                                          int* __restrict__ rk) {
    int e = bid * 256 + threadIdx.x;
    if (e < N_EDGES) {
        rk[e] = atomicAdd(&fc[dst[e]], 1);
        atomicAdd(&cs[src[e]], 1);
    }
}

__device__ __forceinline__ void scat_body(int bid, const int* __restrict__ src,
                                          const int* __restrict__ dst,
                                          const int* __restrict__ rp,
                                          const int* __restrict__ rk,
                                          int* __restrict__ col) {
    int e = bid * 256 + threadIdx.x;
    if (e < N_EDGES) {
        int d = dst[e];
        col[rp[d] + rk[e]] = src[e];
    }
}

// x' = bf16(x*dso), slice-major [6][N][16]
__device__ __forceinline__ void xscale_body(int bid, const float* __restrict__ x,
                                            const float* __restrict__ dso,
                                            unsigned short* __restrict__ xp) {
    int id = bid * 256 + threadIdx.x;
    int n = id / 96, f = id - n * 96;
    float v = (f < FIN_DIM) ? x[(size_t)n * FIN_DIM + f] * dso[n] : 0.f;
    xp[(size_t)(f >> 4) * (N_NODES * 16) + (size_t)n * 16 + (f & 15)] = f2bf(v);
}

__device__ __forceinline__ void wconv_body(int bid, const float* __restrict__ W0,
                                           const float* __restrict__ W1,
                                           const float* __restrict__ W2,
                                           unsigned short* __restrict__ Wt) {
    int id = bid * 256 + threadIdx.x;
    if (id < 256 * 96) {
        int n = id / 96, k = id - n * 96;
        float v = (k < FIN_DIM) ? W0[(size_t)k * H_DIM + n] : 0.f;
        Wt[id] = f2bf(v);
    } else if (id < 256 * 96 + 65536) {
        int id2 = id - 256 * 96;
        int n = id2 >> 8, k = id2 & 255;
        Wt[id] = f2bf(W1[(size_t)k * H_DIM + n]);
    } else {
        int id3 = id - 256 * 96 - 65536;
        int n = id3 >> 8, k = id3 & 255;
        Wt[id] = f2bf(W2[(size_t)k * H_DIM + n]);
    }
}

// XCD-sliced aggregate (slice = local bid & 7)
template<int SW, int NACT, int NSL>
__device__ __forceinline__ void agg_body(int abid, int cg,
                                         const unsigned short* __restrict__ h,
                                         const int* __restrict__ rp,
                                         const int* __restrict__ col,
                                         unsigned short* __restrict__ A) {
    const int CPB = SW / 8;
    const int NPB = 256 / CPB;
    if (cg >= NSL) return;
    int slot = threadIdx.x & (CPB - 1);
    int n = (abid >> 3) * NPB + threadIdx.x / CPB;
    if (n >= N_NODES) return;
    unsigned short* dst = A + (size_t)cg * (N_NODES * SW) + (size_t)n * SW + slot * 8;
    if (cg >= NACT) { us8 z = {}; *(us8*)dst = z; return; }
    const unsigned short* hs = h + (size_t)cg * (N_NODES * SW) + slot * 8;
    int beg = rp[n], end = rp[n + 1];
    float a[8] = {};
    int j = beg;
    for (; j + 3 < end; j += 4) {
        int s0 = col[j], s1 = col[j + 1], s2 = col[j + 2], s3 = col[j + 3];
        us8 v0 = *(const us8*)(hs + (size_t)s0 * SW);
        us8 v1 = *(const us8*)(hs + (size_t)s1 * SW);
        us8 v2 = *(const us8*)(hs + (size_t)s2 * SW);
        us8 v3 = *(const us8*)(hs + (size_t)s3 * SW);
        acc8(a, v0); acc8(a, v1); acc8(a, v2); acc8(a, v3);
    }
    for (; j < end; ++j)
        acc8(a, *(const us8*)(hs + (size_t)col[j] * SW));
    us8 r;
    #pragma unroll
    for (int i = 0; i < 8; ++i) r[i] = f2bf(a[i]);
    *(us8*)dst = r;
}

__device__ __forceinline__ void pool_body(int nb, const unsigned short* __restrict__ h,
                                          const int* __restrict__ gid,
                                          float* __restrict__ pool) {
    int n0 = nb * 64;
    int f = threadIdx.x;
    const unsigned short* hf = h + (size_t)(f >> 5) * (N_NODES * 32) + (f & 31);
    int end = min(n0 + 64, N_NODES);
    float acc = 0.0f;
    int gcur = gid[n0];
    for (int i = n0; i < end; ++i) {
        int g = gid[i];
        if (g != gcur) {
            atomicAdd(&pool[(size_t)gcur * H_DIM + f], acc);
            acc = 0.0f;
            gcur = g;
        }
        acc += bf2f(hf[(size_t)i * 32]);
    }
    atomicAdd(&pool[(size_t)gcur * H_DIM + f], acc);
}

// MFMA GEMM (R9, with full B staging)
template<int K, int SW>
__device__ __forceinline__ void gemm_body(int id, const unsigned short* __restrict__ A,
                                          const unsigned short* __restrict__ Wt,
                                          const float* __restrict__ bias,
                                          const float* __restrict__ dsi,
                                          const float* __restrict__ scale,
                                          unsigned short* __restrict__ C,
                                          unsigned short* smem) {
    unsigned short (*Ah)[40] = (unsigned short(*)[40])smem;
    unsigned short (*Bh)[40] = (unsigned short(*)[40])(smem + 128 * 40);
    const int M = N_NODES;

    int tid = threadIdx.x;
    int lane = tid & 63, wid = tid >> 6;
    int wm = (wid >> 1) * 64, wn = (wid & 1) * 64;
    int bm = (id >> 1) * 128, bn = (id & 1) * 128;

    f32x4 acc[4][4] = {};
    int r0 = wm + (lane & 15);
    int c0 = wn + (lane & 15);
    int kA = (lane >> 4) * 8;

    for (int k0 = 0; k0 < K; k0 += 32) {
        #pragma unroll
        for (int i = 0; i < 2; ++i) {
            int q = tid + i * 256;
            int row = q >> 2, k8 = (q & 3) * 8;
            int gm = bm + row;
            int kk = k0 + k8;
            us8 v = {};
            if (gm < M)
                v = *(const us8*)(A + (size_t)(kk / SW) * ((size_t)N_NODES * SW)
                                    + (size_t)gm * SW + (kk % SW));
            *(us8*)&Ah[row][k8] = v;
        }
        {
            int colx = tid & 127, kg = tid >> 7;
            const unsigned short* wsrc = Wt + (size_t)(bn + colx) * K + k0 + kg * 16;
            us8 w0 = *(const us8*)(wsrc);
            us8 w1 = *(const us8*)(wsrc + 8);
            *(us8*)&Bh[colx][kg * 16] = w0;
            *(us8*)&Bh[colx][kg * 16 + 8] = w1;
        }
        __syncthreads();

        bf16x8 ah[4], bh[4];
        #pragma unroll
        for (int m = 0; m < 4; ++m)
            ah[m] = __builtin_bit_cast(bf16x8, *(const us8*)&Ah[r0 + m * 16][kA]);
        #pragma unroll
        for (int n = 0; n < 4; ++n)
            bh[n] = __builtin_bit_cast(bf16x8, *(const us8*)&Bh[c0 + n * 16][kA]);

        #pragma unroll
        for (int m = 0; m < 4; ++m)
            #pragma unroll
            for (int n = 0; n < 4; ++n)
                acc[m][n] = __builtin_amdgcn_mfma_f32_16x16x32_bf16(ah[m], bh[n], acc[m][n], 0, 0, 0);
        __syncthreads();
    }

    int rowq = (lane >> 4) * 4;
    #pragma unroll
    for (int n = 0; n < 4; ++n) {
        int gn = bn + wn + n * 16 + (lane & 15);
        float bv = bias[gn];
        unsigned short* cs = C + (size_t)(gn >> 5) * (N_NODES * 32) + (gn & 31);
        #pragma unroll
        for (int m = 0; m < 4; ++m) {
            #pragma unroll
            for (int j = 0; j < 4; ++j) {
                int gm = bm + wm + m * 16 + rowq + j;
                if (gm < M) {
                    float r = fmaxf(acc[m][n][j] * dsi[gm] + bv, 0.0f);
                    if (scale) r *= scale[gm];
                    cs[(size_t)gm * 32] = f2bf(r);
                }
            }
        }
    }
}

// ================= kernels =================

__device__ __forceinline__ int block_excl_scan(int v, int* wsums) {
    int lane = threadIdx.x & 63, w = threadIdx.x >> 6;
    int x = v;
    #pragma unroll
    for (int ofs = 1; ofs < 64; ofs <<= 1) {
        int y = __shfl_up(x, ofs, 64);
        if (lane >= ofs) x += y;
    }
    if (lane == 63) wsums[w] = x;
    __syncthreads();
    int wo = 0;
    #pragma unroll
    for (int k = 0; k < 4; ++k) if (k < w) wo += wsums[k];
    return wo + x - v;
}

// wconv || histL || histR — saturate the atomic engine once
__global__ void k_hist2(const float* __restrict__ W0, const float* __restrict__ W1,
                        const float* __restrict__ W2, unsigned short* __restrict__ Wt,
                        const int* __restrict__ srcL, const int* __restrict__ dstL,
                        int* __restrict__ csL, int* __restrict__ fcL, int* __restrict__ rkL,
                        const int* __restrict__ srcR, const int* __restrict__ dstR,
                        int* __restrict__ csR, int* __restrict__ fcR, int* __restrict__ rkR) {
    int bid = blockIdx.x;
    if (bid < WCONV_BLKS)           wconv_body(bid, W0, W1, W2, Wt);
    else if (bid < WCONV_BLKS + EG) hist_body(bid - WCONV_BLKS, srcL, dstL, csL, fcL, rkL);
    else                            hist_body(bid - WCONV_BLKS - EG, srcR, dstR, csR, fcR, rkR);
}

// grid.y selects stream
__global__ void deg_scan1_kernel(const int* __restrict__ csL, const int* __restrict__ fcL,
                                 float* __restrict__ dsoL, float* __restrict__ dsiL,
                                 int* __restrict__ rpL, int* __restrict__ bsL,
                                 const int* __restrict__ csR, const int* __restrict__ fcR,
                                 float* __restrict__ dsoR, float* __restrict__ dsiR,
                                 int* __restrict__ rpR, int* __restrict__ bsR) {
    const int* cs = blockIdx.y ? csR : csL;
    const int* fc = blockIdx.y ? fcR : fcL;
    float* dso = blockIdx.y ? dsoR : dsoL;
    float* dsi = blockIdx.y ? dsiR : dsiL;
    int* rp = blockIdx.y ? rpR : rpL;
    int* bs = blockIdx.y ? bsR : bsL;
    __shared__ int ws[4];
    int i = blockIdx.x * 256 + threadIdx.x;
    int v = 0;
    if (i < N_NODES) {
        dso[i] = rsqrtf(fmaxf((float)cs[i], 1.0f));
        v = fc[i];
        dsi[i] = rsqrtf(fmaxf((float)v, 1.0f));
    }
    int ex = block_excl_scan(v, ws);
    if (i < N_NODES) rp[i] = ex;
    if (threadIdx.x == 255) bs[blockIdx.x] = ex + v;
}

__global__ void scan2_kernel(int* __restrict__ bsL, int* __restrict__ bsR, int nb) {
    int* bs = blockIdx.y ? bsR : bsL;
    __shared__ int ws[4];
    int i = threadIdx.x;
    int v = (i < nb) ? bs[i] : 0;
    int ex = block_excl_scan(v, ws);
    __syncthreads();
    if (i < nb) bs[i] = ex;
}

__global__ void scan3_kernel(int* __restrict__ rpL, const int* __restrict__ bsL,
                             int* __restrict__ rpR, const int* __restrict__ bsR) {
    int* rp = blockIdx.y ? rpR : rpL;
    const int* bs = blockIdx.y ? bsR : bsL;
    int i = blockIdx.x * 256 + threadIdx.x;
    if (i < N_NODES) rp[i] += bs[blockIdx.x];
    if (i == 0) rp[N_NODES] = N_EDGES;
}

// scatL || scatR || xscaleL || xscaleR
__global__ void fuse_ssxx(const int* __restrict__ srcL, const int* __restrict__ dstL,
                          const int* __restrict__ rpL, const int* __restrict__ rkL,
                          int* __restrict__ colL,
                          const int* __restrict__ srcR, const int* __restrict__ dstR,
                          const int* __restrict__ rpR, const int* __restrict__ rkR,
                          int* __restrict__ colR,
                          const float* __restrict__ xL, const float* __restrict__ dsoL,
                          unsigned short* __restrict__ xpL,
                          const float* __restrict__ xR, const float* __restrict__ dsoR,
                          unsigned short* __restrict__ xpR) {
    int bid = blockIdx.x;
    if (bid < EG)                         scat_body(bid, srcL, dstL, rpL, rkL, colL);
    else if (bid < 2 * EG)                scat_body(bid - EG, srcR, dstR, rpR, rkR, colR);
    else if (bid < 2 * EG + XS_BLKS)      xscale_body(bid - 2 * EG, xL, dsoL, xpL);
    else                                  xscale_body(bid - 2 * EG - XS_BLKS, xR, dsoR, xpR);
}

// aggL_i || aggR_i (same layer both streams); NB must be divisible by 8
template<int SW, int NACT, int NSL, int NB>
__global__ void fuse_agg2(const unsigned short* __restrict__ hL, const int* __restrict__ rpL,
                          const int* __restrict__ colL, unsigned short* __restrict__ AL,
                          const unsigned short* __restrict__ hR, const int* __restrict__ rpR,
                          const int* __restrict__ colR, unsigned short* __restrict__ AR) {
    int bid = blockIdx.x;
    if (bid < NB) agg_body<SW, NACT, NSL>(bid, bid & 7, hL, rpL, colL, AL);
    else {
        int lb = bid - NB;
        agg_body<SW, NACT, NSL>(lb, lb & 7, hR, rpR, colR, AR);
    }
}

// gemmL_i + gemmR_i (same K both)
template<int K, int SW>
__global__ __launch_bounds__(256) void gemm_pair2(
        const unsigned short* __restrict__ AL, const float* __restrict__ dsiL,
        const float* __restrict__ scL, unsigned short* __restrict__ CL,
        const unsigned short* __restrict__ AR, const float* __restrict__ dsiR,
        const float* __restrict__ scR, unsigned short* __restrict__ CR,
        const unsigned short* __restrict__ Wt, const float* __restrict__ bias) {
    __shared__ unsigned short smem[2 * 128 * 40];
    int bid = blockIdx.x;
    if (bid < GEMM_BLKS) gemm_body<K, SW>(bid, AL, Wt, bias, dsiL, scL, CL, smem);
    else                 gemm_body<K, SW>(bid - GEMM_BLKS, AR, Wt, bias, dsiR, scR, CR, smem);
}

// poolL || poolR
__global__ void pool2_kernel(const unsigned short* __restrict__ hL, const int* __restrict__ gidL,
                             float* __restrict__ poolL,
                             const unsigned short* __restrict__ hR, const int* __restrict__ gidR,
                             float* __restrict__ poolR) {
    int bid = blockIdx.x;
    if (bid < POOL_BLKS) pool_body(bid, hL, gidL, poolL);
    else                 pool_body(bid - POOL_BLKS, hR, gidR, poolR);
}

__global__ __launch_bounds__(256) void mlp_kernel(
        const float* __restrict__ pl, const float* __restrict__ pr,
        const float* __restrict__ Wf1, const float* __restrict__ bf1,
        const float* __restrict__ Wf2, const float* __restrict__ bf2,
        float* __restrict__ out) {
    __shared__ float z[512];
    __shared__ float red[256];
    int g = blockIdx.x, tid = threadIdx.x;
    z[tid] = pl[(size_t)g * H_DIM + tid];
    z[tid + 256] = pr[(size_t)g * H_DIM + tid];
    __syncthreads();
    float t = bf1[tid];
    #pragma unroll 8
    for (int k = 0; k < 512; ++k) t += z[k] * Wf1[(size_t)k * H_DIM + tid];
    t = fmaxf(t, 0.0f);
    red[tid] = t * Wf2[tid];
    __syncthreads();
    for (int ofs = 128; ofs > 0; ofs >>= 1) {
        if (tid < ofs) red[tid] += red[tid + ofs];
        __syncthreads();
    }
    if (tid == 0) out[g] = red[0] + bf2[0];
}

// ================= driver =================

extern "C" void kernel_launch(void* const* d_in, const int* in_sizes, int n_in,
                              void* d_out, int out_size, void* d_ws, size_t ws_size,
                              hipStream_t stream) {
    const float* xl   = (const float*)d_in[0];
    const float* xr   = (const float*)d_in[1];
    const int* src_l  = (const int*)d_in[2];
    const int* dst_l  = (const int*)d_in[3];
    const int* src_r  = (const int*)d_in[4];
    const int* dst_r  = (const int*)d_in[5];
    const int* gid_l  = (const int*)d_in[6];
    const int* gid_r  = (const int*)d_in[7];
    const float* W0   = (const float*)d_in[8];
    const float* b0   = (const float*)d_in[9];
    const float* W1   = (const float*)d_in[10];
    const float* b1   = (const float*)d_in[11];
    const float* W2   = (const float*)d_in[12];
    const float* b2   = (const float*)d_in[13];
    const float* Wf1  = (const float*)d_in[14];
    const float* bf1  = (const float*)d_in[15];
    const float* Wf2  = (const float*)d_in[16];
    const float* bf2  = (const float*)d_in[17];
    float* out = (float*)d_out;
    (void)in_sizes; (void)n_in; (void)out_size; (void)ws_size;

    size_t off = 0;
    auto carve = [&](size_t bytes) {
        void* p = (char*)d_ws + off;
        off += (bytes + 255) & ~(size_t)255;
        return p;
    };
    const size_t NB4 = (size_t)N_NODES * 4;

    // zero zone (single memset)
    char* zstart = (char*)d_ws;
    int*   cs_l   = (int*)carve(NB4);
    int*   fc_l   = (int*)carve(NB4);
    int*   cs_r   = (int*)carve(NB4);
    int*   fc_r   = (int*)carve(NB4);
    float* pool_l = (float*)carve((size_t)N_GRAPHS * H_DIM * 4);
    float* pool_r = (float*)carve((size_t)N_GRAPHS * H_DIM * 4);
    size_t zbytes = off;

    float* dso_l = (float*)carve(NB4);
    float* dsi_l = (float*)carve(NB4);
    float* dso_r = (float*)carve(NB4);
    float* dsi_r = (float*)carve(NB4);
    int*   rp_l  = (int*)carve((size_t)(N_NODES + 1) * 4);
    int*   rp_r  = (int*)carve((size_t)(N_NODES + 1) * 4);
    int*   col_l = (int*)carve((size_t)N_EDGES * 4);
    int*   col_r = (int*)carve((size_t)N_EDGES * 4);
    int*   rk_l  = (int*)carve((size_t)N_EDGES * 4);
    int*   rk_r  = (int*)carve((size_t)N_EDGES * 4);
    int*   bs_l  = (int*)carve((size_t)SCAN_BLOCKS * 4);
    int*   bs_r  = (int*)carve((size_t)SCAN_BLOCKS * 4);

    unsigned short* Wt    = (unsigned short*)carve((size_t)(256 * 96 + 2 * 65536) * 2);
    unsigned short* Wt0   = Wt;
    unsigned short* Wt1   = Wt + 256 * 96;
    unsigned short* Wt2   = Wt + 256 * 96 + 65536;
    unsigned short* xp_l  = (unsigned short*)carve((size_t)N_NODES * 96 * 2);
    unsigned short* xp_r  = (unsigned short*)carve((size_t)N_NODES * 96 * 2);
    unsigned short* bufA_l = (unsigned short*)carve((size_t)N_NODES * H_DIM * 2);
    unsigned short* bufA_r = (unsigned short*)carve((size_t)N_NODES * H_DIM * 2);
    unsigned short* bufH_l = (unsigned short*)carve((size_t)N_NODES * H_DIM * 2);
    unsigned short* bufH_r = (unsigned short*)carve((size_t)N_NODES * H_DIM * 2);

    hipMemsetAsync(zstart, 0, zbytes, stream);

    // 1. wconv || histL || histR
    k_hist2<<<WCONV_BLKS + 2 * EG, 256, 0, stream>>>(
        W0, W1, W2, Wt,
        src_l, dst_l, cs_l, fc_l, rk_l,
        src_r, dst_r, cs_r, fc_r, rk_r);

    // 2. degrees + scans (both streams via grid.y)
    deg_scan1_kernel<<<dim3(SCAN_BLOCKS, 2), 256, 0, stream>>>(
        cs_l, fc_l, dso_l, dsi_l, rp_l, bs_l,
        cs_r, fc_r, dso_r, dsi_r, rp_r, bs_r);
    scan2_kernel<<<dim3(1, 2), 256, 0, stream>>>(bs_l, bs_r, SCAN_BLOCKS);
    scan3_kernel<<<dim3(SCAN_BLOCKS, 2), 256, 0, stream>>>(rp_l, bs_l, rp_r, bs_r);

    // 3. scatL || scatR || xscaleL || xscaleR
    fuse_ssxx<<<2 * EG + 2 * XS_BLKS, 256, 0, stream>>>(
        src_l, dst_l, rp_l, rk_l, col_l,
        src_r, dst_r, rp_r, rk_r, col_r,
        xl, dso_l, xp_l,
        xr, dso_r, xp_r);

    // 4. layer 0
    fuse_agg2<16, 5, 6, AGG0_BLKS><<<2 * AGG0_BLKS, 256, 0, stream>>>(
        xp_l, rp_l, col_l, bufA_l,
        xp_r, rp_r, col_r, bufA_r);
    gemm_pair2<K0, 16><<<2 * GEMM_BLKS, 256, 0, stream>>>(
        bufA_l, dsi_l, dso_l, bufH_l,
        bufA_r, dsi_r, dso_r, bufH_r,
        Wt0, b0);

    // 5. layer 1
    fuse_agg2<32, 8, 8, AGGH_BLKS><<<2 * AGGH_BLKS, 256, 0, stream>>>(
        bufH_l, rp_l, col_l, bufA_l,
        bufH_r, rp_r, col_r, bufA_r);
    gemm_pair2<H_DIM, 32><<<2 * GEMM_BLKS, 256, 0, stream>>>(
        bufA_l, dsi_l, dso_l, bufH_l,
        bufA_r, dsi_r, dso_r, bufH_r,
        Wt1, b1);

    // 6. layer 2 (no dso scale on output)
    fuse_agg2<32, 8, 8, AGGH_BLKS><<<2 * AGGH_BLKS, 256, 0, stream>>>(
        bufH_l, rp_l, col_l, bufA_l,
        bufH_r, rp_r, col_r, bufA_r);
    gemm_pair2<H_DIM, 32><<<2 * GEMM_BLKS, 256, 0, stream>>>(
        bufA_l, dsi_l, nullptr, bufH_l,
        bufA_r, dsi_r, nullptr, bufH_r,
        Wt2, b2);

    // 7. pools + MLP
    pool2_kernel<<<2 * POOL_BLKS, 256, 0, stream>>>(
        bufH_l, gid_l, pool_l,
        bufH_r, gid_r, pool_r);
    mlp_kernel<<<N_GRAPHS, 256, 0, stream>>>(pool_l, pool_r, Wf1, bf1, Wf2, bf2, out);
}